// Round 1
// baseline (7443.095 us; speedup 1.0000x reference)
//
#include <hip/hip_runtime.h>
#include <math.h>

#define N_ATOMS 40000
#define E_EDGES 640000
#define H 128
#define RBF 64
#define NBLK 3
#define CUTF 5.0f

// stable fast tanh: exp-based, saturates correctly at +/-inf
__device__ __forceinline__ float fast_tanh(float x) {
    return 1.0f - 2.0f / (1.0f + __expf(2.0f * x));
}

// ---------------- K0: x = emb[atom_types] ----------------
__global__ __launch_bounds__(256) void k_embed(const int* __restrict__ types,
                                               const float* __restrict__ emb,
                                               float* __restrict__ x) {
    int flat4 = blockIdx.x * 256 + threadIdx.x;  // over N*H/4 = 1,280,000
    int i = flat4 >> 5;   // 32 float4 per row
    int c4 = flat4 & 31;
    int t = types[i];
    const float4* e4 = (const float4*)(emb + (size_t)t * H);
    ((float4*)(x + (size_t)i * H))[c4] = e4[c4];
}

// ---------------- GEMM (N x H) @ (H x H): 64-atom tile, 128 threads, 8x8 micro ----------------
// EPI 0: out = A@W            (lin1, no bias)
// EPI 1: out = tanh(A@W + b)  (cfconv lin2 + act)
// EPI 2: out = resid + A@W + b (residual update into x)
template <int EPI>
__global__ __launch_bounds__(128, 2) void k_gemm_nh(const float* __restrict__ A,
                                                    const float* __restrict__ W,
                                                    const float* __restrict__ bias,
                                                    float* __restrict__ out,
                                                    const float* __restrict__ resid) {
    __shared__ float at[64 * 133];
    const int tid = threadIdx.x;
    const int abase = blockIdx.x * 64;

    // stage A tile [64][128] -> LDS [e][k], stride 133
#pragma unroll
    for (int i = 0; i < 16; ++i) {
        int flat4 = tid + 128 * i;
        int r = flat4 >> 5, k4 = flat4 & 31;
        float4 v = ((const float4*)(A + (size_t)(abase + r) * H))[k4];
        float* dp = &at[r * 133 + k4 * 4];
        dp[0] = v.x; dp[1] = v.y; dp[2] = v.z; dp[3] = v.w;
    }
    __syncthreads();

    const int eg = tid >> 4, cg = tid & 15;
    const int e0 = eg * 8, c0 = cg * 8;

    float acc[8][8];
#pragma unroll
    for (int i = 0; i < 8; ++i)
#pragma unroll
        for (int j = 0; j < 8; ++j) acc[i][j] = 0.0f;

#pragma unroll 4
    for (int k = 0; k < H; ++k) {
        float a[8];
#pragma unroll
        for (int i = 0; i < 8; ++i) a[i] = at[(e0 + i) * 133 + k];
        const float4 b0 = *(const float4*)(W + (size_t)k * H + c0);
        const float4 b1 = *(const float4*)(W + (size_t)k * H + c0 + 4);
        const float bb[8] = {b0.x, b0.y, b0.z, b0.w, b1.x, b1.y, b1.z, b1.w};
#pragma unroll
        for (int i = 0; i < 8; ++i)
#pragma unroll
            for (int j = 0; j < 8; ++j) acc[i][j] = fmaf(a[i], bb[j], acc[i][j]);
    }

    float bv[8];
    if (EPI >= 1) {
        const float4 q0 = *(const float4*)(bias + c0);
        const float4 q1 = *(const float4*)(bias + c0 + 4);
        bv[0]=q0.x; bv[1]=q0.y; bv[2]=q0.z; bv[3]=q0.w;
        bv[4]=q1.x; bv[5]=q1.y; bv[6]=q1.z; bv[7]=q1.w;
    }

#pragma unroll
    for (int ei = 0; ei < 8; ++ei) {
        const int row = abase + e0 + ei;
        float* op = out + (size_t)row * H + c0;
        float r[8];
#pragma unroll
        for (int j = 0; j < 8; ++j) {
            if (EPI == 0) r[j] = acc[ei][j];
            else if (EPI == 1) r[j] = fast_tanh(acc[ei][j] + bv[j]);
            else r[j] = resid[(size_t)row * H + c0 + j] + acc[ei][j] + bv[j];
        }
        *(float4*)(op)     = make_float4(r[0], r[1], r[2], r[3]);
        *(float4*)(op + 4) = make_float4(r[4], r[5], r[6], r[7]);
    }
}

// ---------------- K2: fused per-edge filter + gather + scatter ----------------
// per 128-edge tile: rbf->LDS, t=tanh(rbf@fw1+b1) via 8x8 GEMM, t->LDS,
// W=(t@fw2+b2)*C, msg=h[src]*W, atomicAdd agg[dst]
__global__ __launch_bounds__(256, 2) void k_edge(const float* __restrict__ ew,
                                                 const int* __restrict__ eidx,
                                                 const float* __restrict__ fw1,
                                                 const float* __restrict__ fb1,
                                                 const float* __restrict__ fw2,
                                                 const float* __restrict__ fb2,
                                                 const float* __restrict__ h,
                                                 float* __restrict__ agg) {
    __shared__ float tile[128 * 133];   // rbf [e][k<64], then t [e][j<128]
    __shared__ float cenv[128];
    __shared__ int ssrc[128];
    __shared__ int sdst[128];

    const int tid = threadIdx.x;
    const int ebase = blockIdx.x * 128;

    // phase 0: rbf + cutoff + indices
    if (tid < 128) {
        const int e = tid;
        const float d = ew[ebase + e];
        const float DELTA = CUTF / 63.0f;
        const float COEFF = -0.5f / (DELTA * DELTA);
#pragma unroll
        for (int k = 0; k < RBF; ++k) {
            float diff = d - (float)k * DELTA;
            tile[e * 133 + k] = __expf(COEFF * diff * diff);
        }
    } else {
        const int e = tid - 128;
        const float d = ew[ebase + e];
        float c = 0.5f * (cosf(0.6283185307179586f * d) + 1.0f);  // pi/CUT = pi/5
        c = (d < CUTF) ? c : 0.0f;
        cenv[e] = c;
        ssrc[e] = eidx[ebase + e];
        sdst[e] = eidx[E_EDGES + ebase + e];
    }
    __syncthreads();

    const int eg = tid >> 4, cg = tid & 15;   // 16 x 16 thread grid
    const int e0 = eg * 8, c0 = cg * 8;

    float acc[8][8];
#pragma unroll
    for (int i = 0; i < 8; ++i)
#pragma unroll
        for (int j = 0; j < 8; ++j) acc[i][j] = 0.0f;

    // GEMM1: t_pre = rbf @ fw1   (k = 0..63)
#pragma unroll 4
    for (int k = 0; k < RBF; ++k) {
        float a[8];
#pragma unroll
        for (int i = 0; i < 8; ++i) a[i] = tile[(e0 + i) * 133 + k];
        const float4 b0 = *(const float4*)(fw1 + (size_t)k * H + c0);
        const float4 b1 = *(const float4*)(fw1 + (size_t)k * H + c0 + 4);
        const float bb[8] = {b0.x, b0.y, b0.z, b0.w, b1.x, b1.y, b1.z, b1.w};
#pragma unroll
        for (int i = 0; i < 8; ++i)
#pragma unroll
            for (int j = 0; j < 8; ++j) acc[i][j] = fmaf(a[i], bb[j], acc[i][j]);
    }

    // bias + tanh (in place)
    {
        const float4 q0 = *(const float4*)(fb1 + c0);
        const float4 q1 = *(const float4*)(fb1 + c0 + 4);
        const float bv[8] = {q0.x, q0.y, q0.z, q0.w, q1.x, q1.y, q1.z, q1.w};
#pragma unroll
        for (int i = 0; i < 8; ++i)
#pragma unroll
            for (int j = 0; j < 8; ++j) acc[i][j] = fast_tanh(acc[i][j] + bv[j]);
    }

    __syncthreads();  // everyone done reading rbf region

    // write t tile [e][j]
#pragma unroll
    for (int i = 0; i < 8; ++i)
#pragma unroll
        for (int j = 0; j < 8; ++j) tile[(e0 + i) * 133 + c0 + j] = acc[i][j];
    __syncthreads();

    // GEMM2: W_pre = t @ fw2  (j = 0..127)
#pragma unroll
    for (int i = 0; i < 8; ++i)
#pragma unroll
        for (int j = 0; j < 8; ++j) acc[i][j] = 0.0f;

#pragma unroll 4
    for (int k = 0; k < H; ++k) {
        float a[8];
#pragma unroll
        for (int i = 0; i < 8; ++i) a[i] = tile[(e0 + i) * 133 + k];
        const float4 b0 = *(const float4*)(fw2 + (size_t)k * H + c0);
        const float4 b1 = *(const float4*)(fw2 + (size_t)k * H + c0 + 4);
        const float bb[8] = {b0.x, b0.y, b0.z, b0.w, b1.x, b1.y, b1.z, b1.w};
#pragma unroll
        for (int i = 0; i < 8; ++i)
#pragma unroll
            for (int j = 0; j < 8; ++j) acc[i][j] = fmaf(a[i], bb[j], acc[i][j]);
    }

    // epilogue: W = (acc + fb2) * C; msg = h[src] * W; atomicAdd agg[dst]
    const float4 q0 = *(const float4*)(fb2 + c0);
    const float4 q1 = *(const float4*)(fb2 + c0 + 4);
    const float bv[8] = {q0.x, q0.y, q0.z, q0.w, q1.x, q1.y, q1.z, q1.w};

#pragma unroll
    for (int ei = 0; ei < 8; ++ei) {
        const int el = e0 + ei;
        const float ce = cenv[el];
        const int s = ssrc[el];
        const int dd = sdst[el];
        const float4 h0 = *(const float4*)(h + (size_t)s * H + c0);
        const float4 h1 = *(const float4*)(h + (size_t)s * H + c0 + 4);
        const float hv[8] = {h0.x, h0.y, h0.z, h0.w, h1.x, h1.y, h1.z, h1.w};
        float* ap = agg + (size_t)dd * H + c0;
#pragma unroll
        for (int j = 0; j < 8; ++j) {
            float msg = (acc[ei][j] + bv[j]) * ce * hv[j];
            atomicAdd(ap + j, msg);
        }
    }
}

// ---------------- K5: energy = tanh(x @ o1 + b1) @ o2 + b2 ----------------
__global__ __launch_bounds__(64) void k_out(const float* __restrict__ x,
                                            const float* __restrict__ o1w,
                                            const float* __restrict__ o1b,
                                            const float* __restrict__ o2w,
                                            const float* __restrict__ o2b,
                                            float* __restrict__ out) {
    __shared__ float xs[64 * 133];
    const int tid = threadIdx.x;
    const int abase = blockIdx.x * 64;

#pragma unroll
    for (int i = 0; i < 32; ++i) {
        int flat4 = tid + 64 * i;
        int r = flat4 >> 5, k4 = flat4 & 31;
        float4 v = ((const float4*)(x + (size_t)(abase + r) * H))[k4];
        float* dp = &xs[r * 133 + k4 * 4];
        dp[0] = v.x; dp[1] = v.y; dp[2] = v.z; dp[3] = v.w;
    }
    __syncthreads();

    float energy = o2b[0];
    for (int j = 0; j < 64; ++j) {
        float a = o1b[j];
#pragma unroll 8
        for (int k = 0; k < H; ++k) a = fmaf(xs[tid * 133 + k], o1w[(size_t)k * 64 + j], a);
        energy = fmaf(fast_tanh(a), o2w[j], energy);
    }
    out[abase + tid] = energy;
}

extern "C" void kernel_launch(void* const* d_in, const int* in_sizes, int n_in,
                              void* d_out, int out_size, void* d_ws, size_t ws_size,
                              hipStream_t stream) {
    const int*   types = (const int*)d_in[0];
    const int*   eidx  = (const int*)d_in[1];
    const float* ew    = (const float*)d_in[2];
    const float* emb   = (const float*)d_in[3];
    const float* lin1  = (const float*)d_in[4];
    const float* fw1   = (const float*)d_in[5];
    const float* fb1   = (const float*)d_in[6];
    const float* fw2   = (const float*)d_in[7];
    const float* fb2   = (const float*)d_in[8];
    const float* lin2  = (const float*)d_in[9];
    const float* lin2b = (const float*)d_in[10];
    const float* linw  = (const float*)d_in[11];
    const float* linb  = (const float*)d_in[12];
    const float* o1w   = (const float*)d_in[13];
    const float* o1b   = (const float*)d_in[14];
    const float* o2w   = (const float*)d_in[15];
    const float* o2b   = (const float*)d_in[16];
    float* out = (float*)d_out;

    float* x   = (float*)d_ws;                    // N*H
    float* h   = x + (size_t)N_ATOMS * H;         // N*H (also reused as u)
    float* agg = h + (size_t)N_ATOMS * H;         // N*H

    k_embed<<<5000, 256, 0, stream>>>(types, emb, x);

    for (int b = 0; b < NBLK; ++b) {
        // h = x @ lin1[b]
        k_gemm_nh<0><<<625, 128, 0, stream>>>(x, lin1 + (size_t)b * H * H, nullptr, h, nullptr);
        // agg = 0
        hipMemsetAsync(agg, 0, (size_t)N_ATOMS * H * sizeof(float), stream);
        // fused filter + message + scatter
        k_edge<<<5000, 256, 0, stream>>>(ew, eidx,
                                         fw1 + (size_t)b * RBF * H, fb1 + (size_t)b * H,
                                         fw2 + (size_t)b * H * H, fb2 + (size_t)b * H,
                                         h, agg);
        // u = tanh(agg @ lin2[b] + lin2_b[b])   (u aliases h)
        k_gemm_nh<1><<<625, 128, 0, stream>>>(agg, lin2 + (size_t)b * H * H, lin2b + (size_t)b * H, h, nullptr);
        // x = x + u @ lin_w[b] + lin_b[b]
        k_gemm_nh<2><<<625, 128, 0, stream>>>(h, linw + (size_t)b * H * H, linb + (size_t)b * H, x, x);
    }

    k_out<<<625, 64, 0, stream>>>(x, o1w, o1b, o2w, o2b, out);
}

// Round 2
// 1921.097 us; speedup vs baseline: 3.8744x; 3.8744x over previous
//
#include <hip/hip_runtime.h>
#include <math.h>

#define N_ATOMS 40000
#define E_EDGES 640000
#define H 128
#define RBF 64
#define NBLK 3
#define CUTF 5.0f

// stable fast tanh: exp-based, saturates correctly at +/-inf
__device__ __forceinline__ float fast_tanh(float x) {
    return 1.0f - 2.0f / (1.0f + __expf(2.0f * x));
}

// ---------------- K0: x = emb[atom_types] ----------------
__global__ __launch_bounds__(256) void k_embed(const int* __restrict__ types,
                                               const float* __restrict__ emb,
                                               float* __restrict__ x) {
    int flat4 = blockIdx.x * 256 + threadIdx.x;  // over N*H/4 = 1,280,000
    int i = flat4 >> 5;   // 32 float4 per row
    int c4 = flat4 & 31;
    int t = types[i];
    const float4* e4 = (const float4*)(emb + (size_t)t * H);
    ((float4*)(x + (size_t)i * H))[c4] = e4[c4];
}

// ---------------- CSR build: count, scan, fill (dst-sorted edge permutation) ----------------
__global__ __launch_bounds__(256) void k_count(const int* __restrict__ eidx,
                                               int* __restrict__ cnt) {
    int e = blockIdx.x * 256 + threadIdx.x;
    atomicAdd(&cnt[eidx[E_EDGES + e]], 1);
}

// single-block exclusive scan of cnt[N_ATOMS] -> cursor
__global__ __launch_bounds__(1024) void k_scan(const int* __restrict__ cnt,
                                               int* __restrict__ cursor) {
    __shared__ int buf[1024];
    const int tid = threadIdx.x;
    int carry = 0;  // identical in all threads
    for (int base = 0; base < N_ATOMS; base += 1024) {
        int idx = base + tid;
        int v = (idx < N_ATOMS) ? cnt[idx] : 0;
        buf[tid] = v;
        __syncthreads();
#pragma unroll
        for (int off = 1; off < 1024; off <<= 1) {
            int t = (tid >= off) ? buf[tid - off] : 0;
            __syncthreads();
            buf[tid] += t;
            __syncthreads();
        }
        if (idx < N_ATOMS) cursor[idx] = buf[tid] - v + carry;  // exclusive
        carry += buf[1023];
        __syncthreads();  // protect buf before next chunk
    }
}

__global__ __launch_bounds__(256) void k_fill(const int* __restrict__ eidx,
                                              const float* __restrict__ ew,
                                              int* __restrict__ cursor,
                                              float* __restrict__ pew,
                                              int* __restrict__ psrc,
                                              int* __restrict__ pdst) {
    int e = blockIdx.x * 256 + threadIdx.x;
    int dd = eidx[E_EDGES + e];
    int pos = atomicAdd(&cursor[dd], 1);
    pew[pos] = ew[e];
    psrc[pos] = eidx[e];
    pdst[pos] = dd;
}

// ---------------- GEMM (N x H) @ (H x H): 64-atom tile, 128 threads, 8x8 micro ----------------
// EPI 0: out = A@W            (lin1, no bias)
// EPI 1: out = tanh(A@W + b)  (cfconv lin2 + act)
// EPI 2: out = resid + A@W + b (residual update into x)
template <int EPI>
__global__ __launch_bounds__(128, 2) void k_gemm_nh(const float* __restrict__ A,
                                                    const float* __restrict__ W,
                                                    const float* __restrict__ bias,
                                                    float* __restrict__ out,
                                                    const float* __restrict__ resid) {
    __shared__ float at[64 * 133];
    const int tid = threadIdx.x;
    const int abase = blockIdx.x * 64;

#pragma unroll
    for (int i = 0; i < 16; ++i) {
        int flat4 = tid + 128 * i;
        int r = flat4 >> 5, k4 = flat4 & 31;
        float4 v = ((const float4*)(A + (size_t)(abase + r) * H))[k4];
        float* dp = &at[r * 133 + k4 * 4];
        dp[0] = v.x; dp[1] = v.y; dp[2] = v.z; dp[3] = v.w;
    }
    __syncthreads();

    const int eg = tid >> 4, cg = tid & 15;
    const int e0 = eg * 8, c0 = cg * 8;

    float acc[8][8];
#pragma unroll
    for (int i = 0; i < 8; ++i)
#pragma unroll
        for (int j = 0; j < 8; ++j) acc[i][j] = 0.0f;

#pragma unroll 4
    for (int k = 0; k < H; ++k) {
        float a[8];
#pragma unroll
        for (int i = 0; i < 8; ++i) a[i] = at[(e0 + i) * 133 + k];
        const float4 b0 = *(const float4*)(W + (size_t)k * H + c0);
        const float4 b1 = *(const float4*)(W + (size_t)k * H + c0 + 4);
        const float bb[8] = {b0.x, b0.y, b0.z, b0.w, b1.x, b1.y, b1.z, b1.w};
#pragma unroll
        for (int i = 0; i < 8; ++i)
#pragma unroll
            for (int j = 0; j < 8; ++j) acc[i][j] = fmaf(a[i], bb[j], acc[i][j]);
    }

    float bv[8];
    if (EPI >= 1) {
        const float4 q0 = *(const float4*)(bias + c0);
        const float4 q1 = *(const float4*)(bias + c0 + 4);
        bv[0]=q0.x; bv[1]=q0.y; bv[2]=q0.z; bv[3]=q0.w;
        bv[4]=q1.x; bv[5]=q1.y; bv[6]=q1.z; bv[7]=q1.w;
    }

#pragma unroll
    for (int ei = 0; ei < 8; ++ei) {
        const int row = abase + e0 + ei;
        float* op = out + (size_t)row * H + c0;
        float r[8];
#pragma unroll
        for (int j = 0; j < 8; ++j) {
            if (EPI == 0) r[j] = acc[ei][j];
            else if (EPI == 1) r[j] = fast_tanh(acc[ei][j] + bv[j]);
            else r[j] = resid[(size_t)row * H + c0 + j] + acc[ei][j] + bv[j];
        }
        *(float4*)(op)     = make_float4(r[0], r[1], r[2], r[3]);
        *(float4*)(op + 4) = make_float4(r[4], r[5], r[6], r[7]);
    }
}

// ---------------- K2: fused per-edge filter + gather + SORTED segmented scatter ----------------
// edges arrive dst-sorted (pew/psrc/pdst). per 128-edge tile:
//   rbf->LDS, t=tanh(rbf@fw1+b1), t->LDS, W=(t@fw2+b2)*C, msg=h[src]*W -> LDS,
//   then 128-col x 2-half segmented reduction over sorted dst runs.
// Runs strictly interior to a half are exclusively owned -> plain store;
// runs touching e in {0,64,128} -> atomicAdd. ~512 atomics/block vs 16384.
__global__ __launch_bounds__(256, 2) void k_edge(const float* __restrict__ pew,
                                                 const int* __restrict__ psrc,
                                                 const int* __restrict__ pdst,
                                                 const float* __restrict__ fw1,
                                                 const float* __restrict__ fb1,
                                                 const float* __restrict__ fw2,
                                                 const float* __restrict__ fb2,
                                                 const float* __restrict__ h,
                                                 float* __restrict__ agg) {
    __shared__ float tile[128 * 133];   // rbf [e][k<64] -> t [e][j<128] -> msg [e][j<128]
    __shared__ float cenv[128];
    __shared__ int ssrc[128];
    __shared__ int sdst[128];

    const int tid = threadIdx.x;
    const int ebase = blockIdx.x * 128;

    // phase 0: rbf + cutoff + indices (from pre-permuted arrays)
    if (tid < 128) {
        const int e = tid;
        const float d = pew[ebase + e];
        const float DELTA = CUTF / 63.0f;
        const float COEFF = -0.5f / (DELTA * DELTA);
#pragma unroll
        for (int k = 0; k < RBF; ++k) {
            float diff = d - (float)k * DELTA;
            tile[e * 133 + k] = __expf(COEFF * diff * diff);
        }
    } else {
        const int e = tid - 128;
        const float d = pew[ebase + e];
        float c = 0.5f * (cosf(0.6283185307179586f * d) + 1.0f);  // pi/CUT
        c = (d < CUTF) ? c : 0.0f;
        cenv[e] = c;
        ssrc[e] = psrc[ebase + e];
        sdst[e] = pdst[ebase + e];
    }
    __syncthreads();

    const int eg = tid >> 4, cg = tid & 15;   // 16 x 16 thread grid
    const int e0 = eg * 8, c0 = cg * 8;

    float acc[8][8];
#pragma unroll
    for (int i = 0; i < 8; ++i)
#pragma unroll
        for (int j = 0; j < 8; ++j) acc[i][j] = 0.0f;

    // GEMM1: t_pre = rbf @ fw1   (k = 0..63)
#pragma unroll 4
    for (int k = 0; k < RBF; ++k) {
        float a[8];
#pragma unroll
        for (int i = 0; i < 8; ++i) a[i] = tile[(e0 + i) * 133 + k];
        const float4 b0 = *(const float4*)(fw1 + (size_t)k * H + c0);
        const float4 b1 = *(const float4*)(fw1 + (size_t)k * H + c0 + 4);
        const float bb[8] = {b0.x, b0.y, b0.z, b0.w, b1.x, b1.y, b1.z, b1.w};
#pragma unroll
        for (int i = 0; i < 8; ++i)
#pragma unroll
            for (int j = 0; j < 8; ++j) acc[i][j] = fmaf(a[i], bb[j], acc[i][j]);
    }

    // bias + tanh
    {
        const float4 q0 = *(const float4*)(fb1 + c0);
        const float4 q1 = *(const float4*)(fb1 + c0 + 4);
        const float bv[8] = {q0.x, q0.y, q0.z, q0.w, q1.x, q1.y, q1.z, q1.w};
#pragma unroll
        for (int i = 0; i < 8; ++i)
#pragma unroll
            for (int j = 0; j < 8; ++j) acc[i][j] = fast_tanh(acc[i][j] + bv[j]);
    }

    __syncthreads();  // rbf region reads complete

#pragma unroll
    for (int i = 0; i < 8; ++i)
#pragma unroll
        for (int j = 0; j < 8; ++j) tile[(e0 + i) * 133 + c0 + j] = acc[i][j];
    __syncthreads();

    // GEMM2: W_pre = t @ fw2  (k = 0..127)
#pragma unroll
    for (int i = 0; i < 8; ++i)
#pragma unroll
        for (int j = 0; j < 8; ++j) acc[i][j] = 0.0f;

#pragma unroll 4
    for (int k = 0; k < H; ++k) {
        float a[8];
#pragma unroll
        for (int i = 0; i < 8; ++i) a[i] = tile[(e0 + i) * 133 + k];
        const float4 b0 = *(const float4*)(fw2 + (size_t)k * H + c0);
        const float4 b1 = *(const float4*)(fw2 + (size_t)k * H + c0 + 4);
        const float bb[8] = {b0.x, b0.y, b0.z, b0.w, b1.x, b1.y, b1.z, b1.w};
#pragma unroll
        for (int i = 0; i < 8; ++i)
#pragma unroll
            for (int j = 0; j < 8; ++j) acc[i][j] = fmaf(a[i], bb[j], acc[i][j]);
    }

    // epilogue: msg = (acc + fb2) * C * h[src]  -> LDS (overwrite tile)
    const float4 q0 = *(const float4*)(fb2 + c0);
    const float4 q1 = *(const float4*)(fb2 + c0 + 4);
    const float bv[8] = {q0.x, q0.y, q0.z, q0.w, q1.x, q1.y, q1.z, q1.w};

    __syncthreads();  // all GEMM2 reads of tile complete before overwrite

#pragma unroll
    for (int ei = 0; ei < 8; ++ei) {
        const int el = e0 + ei;
        const float ce = cenv[el];
        const int s = ssrc[el];
        const float4 h0 = *(const float4*)(h + (size_t)s * H + c0);
        const float4 h1 = *(const float4*)(h + (size_t)s * H + c0 + 4);
        const float hv[8] = {h0.x, h0.y, h0.z, h0.w, h1.x, h1.y, h1.z, h1.w};
#pragma unroll
        for (int j = 0; j < 8; ++j)
            tile[el * 133 + c0 + j] = (acc[ei][j] + bv[j]) * ce * hv[j];
    }
    __syncthreads();

    // segmented reduction: thread = (col, half); runs of equal dst are summed,
    // interior runs plain-stored (exclusive ownership), boundary runs atomic.
    {
        const int col = tid & 127;
        const int half = tid >> 7;
        const int lo = half * 64, hi = lo + 64;
        int cur = sdst[lo];
        float sum = tile[lo * 133 + col];
        int s = lo;
        for (int e = lo + 1; e < hi; ++e) {
            const int dn = sdst[e];
            const float v = tile[e * 133 + col];
            if (dn != cur) {
                float* ap = agg + (size_t)cur * H + col;
                if (s > lo) *ap = sum;          // run [s,e): global start & end
                else atomicAdd(ap, sum);        // touches lower boundary
                cur = dn; sum = v; s = e;
            } else {
                sum += v;
            }
        }
        // final run touches upper boundary -> always atomic
        atomicAdd(agg + (size_t)cur * H + col, sum);
    }
}

// ---------------- K5: energy = tanh(x @ o1 + b1) @ o2 + b2 ----------------
__global__ __launch_bounds__(64) void k_out(const float* __restrict__ x,
                                            const float* __restrict__ o1w,
                                            const float* __restrict__ o1b,
                                            const float* __restrict__ o2w,
                                            const float* __restrict__ o2b,
                                            float* __restrict__ out) {
    __shared__ float xs[64 * 133];
    const int tid = threadIdx.x;
    const int abase = blockIdx.x * 64;

#pragma unroll
    for (int i = 0; i < 32; ++i) {
        int flat4 = tid + 64 * i;
        int r = flat4 >> 5, k4 = flat4 & 31;
        float4 v = ((const float4*)(x + (size_t)(abase + r) * H))[k4];
        float* dp = &xs[r * 133 + k4 * 4];
        dp[0] = v.x; dp[1] = v.y; dp[2] = v.z; dp[3] = v.w;
    }
    __syncthreads();

    float energy = o2b[0];
    for (int j = 0; j < 64; ++j) {
        float a = o1b[j];
#pragma unroll 8
        for (int k = 0; k < H; ++k) a = fmaf(xs[tid * 133 + k], o1w[(size_t)k * 64 + j], a);
        energy = fmaf(fast_tanh(a), o2w[j], energy);
    }
    out[abase + tid] = energy;
}

extern "C" void kernel_launch(void* const* d_in, const int* in_sizes, int n_in,
                              void* d_out, int out_size, void* d_ws, size_t ws_size,
                              hipStream_t stream) {
    const int*   types = (const int*)d_in[0];
    const int*   eidx  = (const int*)d_in[1];
    const float* ew    = (const float*)d_in[2];
    const float* emb   = (const float*)d_in[3];
    const float* lin1  = (const float*)d_in[4];
    const float* fw1   = (const float*)d_in[5];
    const float* fb1   = (const float*)d_in[6];
    const float* fw2   = (const float*)d_in[7];
    const float* fb2   = (const float*)d_in[8];
    const float* lin2  = (const float*)d_in[9];
    const float* lin2b = (const float*)d_in[10];
    const float* linw  = (const float*)d_in[11];
    const float* linb  = (const float*)d_in[12];
    const float* o1w   = (const float*)d_in[13];
    const float* o1b   = (const float*)d_in[14];
    const float* o2w   = (const float*)d_in[15];
    const float* o2b   = (const float*)d_in[16];
    float* out = (float*)d_out;

    // ws carve (all 16B-aligned offsets)
    float* x      = (float*)d_ws;                       // N*H
    float* h      = x + (size_t)N_ATOMS * H;            // N*H (also reused as u)
    float* agg    = h + (size_t)N_ATOMS * H;            // N*H
    int*   cnt    = (int*)(agg + (size_t)N_ATOMS * H);  // N
    int*   cursor = cnt + N_ATOMS;                      // N
    int*   psrc   = cursor + N_ATOMS;                   // E
    int*   pdst   = psrc + E_EDGES;                     // E
    float* pew    = (float*)(pdst + E_EDGES);           // E

    // ---- build dst-sorted edge arrays (same work every call) ----
    hipMemsetAsync(cnt, 0, N_ATOMS * sizeof(int), stream);
    k_count<<<E_EDGES / 256, 256, 0, stream>>>(eidx, cnt);
    k_scan<<<1, 1024, 0, stream>>>(cnt, cursor);
    k_fill<<<E_EDGES / 256, 256, 0, stream>>>(eidx, ew, cursor, pew, psrc, pdst);

    k_embed<<<(N_ATOMS * H / 4) / 256, 256, 0, stream>>>(types, emb, x);

    for (int b = 0; b < NBLK; ++b) {
        // h = x @ lin1[b]
        k_gemm_nh<0><<<N_ATOMS / 64, 128, 0, stream>>>(x, lin1 + (size_t)b * H * H, nullptr, h, nullptr);
        // agg = 0
        hipMemsetAsync(agg, 0, (size_t)N_ATOMS * H * sizeof(float), stream);
        // fused filter + message + sorted segmented scatter
        k_edge<<<E_EDGES / 128, 256, 0, stream>>>(pew, psrc, pdst,
                                                  fw1 + (size_t)b * RBF * H, fb1 + (size_t)b * H,
                                                  fw2 + (size_t)b * H * H, fb2 + (size_t)b * H,
                                                  h, agg);
        // u = tanh(agg @ lin2[b] + lin2_b[b])   (u aliases h)
        k_gemm_nh<1><<<N_ATOMS / 64, 128, 0, stream>>>(agg, lin2 + (size_t)b * H * H, lin2b + (size_t)b * H, h, nullptr);
        // x = x + u @ lin_w[b] + lin_b[b]
        k_gemm_nh<2><<<N_ATOMS / 64, 128, 0, stream>>>(h, linw + (size_t)b * H * H, linb + (size_t)b * H, x, x);
    }

    k_out<<<N_ATOMS / 64, 64, 0, stream>>>(x, o1w, o1b, o2w, o2b, out);
}

// Round 3
// 896.969 us; speedup vs baseline: 8.2981x; 2.1418x over previous
//
#include <hip/hip_runtime.h>
#include <math.h>

#define N_ATOMS 40000
#define E_EDGES 640000
#define H 128
#define RBF 64
#define NBLK 3
#define CUTF 5.0f
#define TBL 8192   // filter lookup table entries per interaction block

// stable fast tanh: exp-based, saturates correctly at +/-inf
__device__ __forceinline__ float fast_tanh(float x) {
    return 1.0f - 2.0f / (1.0f + __expf(2.0f * x));
}

// ---------------- K0: x = emb[atom_types] ----------------
__global__ __launch_bounds__(256) void k_embed(const int* __restrict__ types,
                                               const float* __restrict__ emb,
                                               float* __restrict__ x) {
    int flat4 = blockIdx.x * 256 + threadIdx.x;  // over N*H/4
    int i = flat4 >> 5;   // 32 float4 per row
    int c4 = flat4 & 31;
    int t = types[i];
    const float4* e4 = (const float4*)(emb + (size_t)t * H);
    ((float4*)(x + (size_t)i * H))[c4] = e4[c4];
}

// ---------------- CSR build: count, scan, fill (dst-sorted edge permutation) ----------------
__global__ __launch_bounds__(256) void k_count(const int* __restrict__ eidx,
                                               int* __restrict__ cnt) {
    int e = blockIdx.x * 256 + threadIdx.x;
    atomicAdd(&cnt[eidx[E_EDGES + e]], 1);
}

__global__ __launch_bounds__(1024) void k_scan(const int* __restrict__ cnt,
                                               int* __restrict__ cursor) {
    __shared__ int buf[1024];
    const int tid = threadIdx.x;
    int carry = 0;
    for (int base = 0; base < N_ATOMS; base += 1024) {
        int idx = base + tid;
        int v = (idx < N_ATOMS) ? cnt[idx] : 0;
        buf[tid] = v;
        __syncthreads();
#pragma unroll
        for (int off = 1; off < 1024; off <<= 1) {
            int t = (tid >= off) ? buf[tid - off] : 0;
            __syncthreads();
            buf[tid] += t;
            __syncthreads();
        }
        if (idx < N_ATOMS) cursor[idx] = buf[tid] - v + carry;  // exclusive
        carry += buf[1023];
        __syncthreads();
    }
}

__global__ __launch_bounds__(256) void k_fill(const int* __restrict__ eidx,
                                              const float* __restrict__ ew,
                                              int* __restrict__ cursor,
                                              float* __restrict__ pew,
                                              int* __restrict__ psrc,
                                              int* __restrict__ pdst) {
    int e = blockIdx.x * 256 + threadIdx.x;
    int dd = eidx[E_EDGES + e];
    int pos = atomicAdd(&cursor[dd], 1);
    pew[pos] = ew[e];
    psrc[pos] = eidx[e];
    pdst[pos] = dd;
}

// ---------------- K1: filter table build ----------------
// tab[b][m][j] = (tanh(rbf(d_m)@fw1[b]+fb1[b]) @ fw2[b] + fb2[b])[j] * C(d_m),
// d_m = m * CUT/(TBL-1).  128 entries per block, 256 threads, 8x8 micro-GEMM.
__global__ __launch_bounds__(256, 2) void k_table(const float* __restrict__ fw1all,
                                                  const float* __restrict__ fb1all,
                                                  const float* __restrict__ fw2all,
                                                  const float* __restrict__ fb2all,
                                                  float* __restrict__ tab) {
    const int b = blockIdx.y;
    const float* fw1 = fw1all + (size_t)b * RBF * H;
    const float* fb1 = fb1all + (size_t)b * H;
    const float* fw2 = fw2all + (size_t)b * H * H;
    const float* fb2 = fb2all + (size_t)b * H;
    float* tabB = tab + (size_t)b * TBL * H;

    __shared__ float tile[128 * 133];
    const int tid = threadIdx.x;
    const int mbase = blockIdx.x * 128;
    const float DSTEP = CUTF / (float)(TBL - 1);

    // phase 0: rbf rows (each thread: 32 of the 64 rbf values of one entry)
    {
        const int e = tid & 127;
        const int k0 = (tid >> 7) * 32;
        const float d = (float)(mbase + e) * DSTEP;
        const float DELTA = CUTF / 63.0f;
        const float COEFF = -0.5f / (DELTA * DELTA);
#pragma unroll
        for (int k = k0; k < k0 + 32; ++k) {
            float diff = d - (float)k * DELTA;
            tile[e * 133 + k] = __expf(COEFF * diff * diff);
        }
    }
    __syncthreads();

    const int eg = tid >> 4, cg = tid & 15;
    const int e0 = eg * 8, c0 = cg * 8;

    float acc[8][8];
#pragma unroll
    for (int i = 0; i < 8; ++i)
#pragma unroll
        for (int j = 0; j < 8; ++j) acc[i][j] = 0.0f;

    // GEMM1: rbf @ fw1 (k = 0..63)
#pragma unroll 4
    for (int k = 0; k < RBF; ++k) {
        float a[8];
#pragma unroll
        for (int i = 0; i < 8; ++i) a[i] = tile[(e0 + i) * 133 + k];
        const float4 b0 = *(const float4*)(fw1 + (size_t)k * H + c0);
        const float4 b1 = *(const float4*)(fw1 + (size_t)k * H + c0 + 4);
        const float bb[8] = {b0.x, b0.y, b0.z, b0.w, b1.x, b1.y, b1.z, b1.w};
#pragma unroll
        for (int i = 0; i < 8; ++i)
#pragma unroll
            for (int j = 0; j < 8; ++j) acc[i][j] = fmaf(a[i], bb[j], acc[i][j]);
    }

    // bias + tanh
    {
        const float4 q0 = *(const float4*)(fb1 + c0);
        const float4 q1 = *(const float4*)(fb1 + c0 + 4);
        const float bv[8] = {q0.x, q0.y, q0.z, q0.w, q1.x, q1.y, q1.z, q1.w};
#pragma unroll
        for (int i = 0; i < 8; ++i)
#pragma unroll
            for (int j = 0; j < 8; ++j) acc[i][j] = fast_tanh(acc[i][j] + bv[j]);
    }

    __syncthreads();
#pragma unroll
    for (int i = 0; i < 8; ++i)
#pragma unroll
        for (int j = 0; j < 8; ++j) tile[(e0 + i) * 133 + c0 + j] = acc[i][j];
    __syncthreads();

    // GEMM2: t @ fw2 (k = 0..127)
#pragma unroll
    for (int i = 0; i < 8; ++i)
#pragma unroll
        for (int j = 0; j < 8; ++j) acc[i][j] = 0.0f;

#pragma unroll 4
    for (int k = 0; k < H; ++k) {
        float a[8];
#pragma unroll
        for (int i = 0; i < 8; ++i) a[i] = tile[(e0 + i) * 133 + k];
        const float4 b0 = *(const float4*)(fw2 + (size_t)k * H + c0);
        const float4 b1 = *(const float4*)(fw2 + (size_t)k * H + c0 + 4);
        const float bb[8] = {b0.x, b0.y, b0.z, b0.w, b1.x, b1.y, b1.z, b1.w};
#pragma unroll
        for (int i = 0; i < 8; ++i)
#pragma unroll
            for (int j = 0; j < 8; ++j) acc[i][j] = fmaf(a[i], bb[j], acc[i][j]);
    }

    // epilogue: (acc + fb2) * C(d) -> tab row
    const float4 q0 = *(const float4*)(fb2 + c0);
    const float4 q1 = *(const float4*)(fb2 + c0 + 4);
    const float bv[8] = {q0.x, q0.y, q0.z, q0.w, q1.x, q1.y, q1.z, q1.w};

#pragma unroll
    for (int ei = 0; ei < 8; ++ei) {
        const int m = mbase + e0 + ei;
        const float d = (float)m * DSTEP;
        float c = 0.5f * (cosf(0.6283185307179586f * d) + 1.0f);
        c = (d < CUTF) ? c : 0.0f;
        float* op = tabB + (size_t)m * H + c0;
        float r[8];
#pragma unroll
        for (int j = 0; j < 8; ++j) r[j] = (acc[ei][j] + bv[j]) * c;
        *(float4*)(op)     = make_float4(r[0], r[1], r[2], r[3]);
        *(float4*)(op + 4) = make_float4(r[4], r[5], r[6], r[7]);
    }
}

// ---------------- GEMM (N x H) @ (H x H), EPI 0: out = A@W (lin1) ----------------
template <int EPI>
__global__ __launch_bounds__(128, 2) void k_gemm_nh(const float* __restrict__ A,
                                                    const float* __restrict__ W,
                                                    float* __restrict__ out) {
    __shared__ float at[64 * 133];
    const int tid = threadIdx.x;
    const int abase = blockIdx.x * 64;

#pragma unroll
    for (int i = 0; i < 16; ++i) {
        int flat4 = tid + 128 * i;
        int r = flat4 >> 5, k4 = flat4 & 31;
        float4 v = ((const float4*)(A + (size_t)(abase + r) * H))[k4];
        float* dp = &at[r * 133 + k4 * 4];
        dp[0] = v.x; dp[1] = v.y; dp[2] = v.z; dp[3] = v.w;
    }
    __syncthreads();

    const int eg = tid >> 4, cg = tid & 15;
    const int e0 = eg * 8, c0 = cg * 8;

    float acc[8][8];
#pragma unroll
    for (int i = 0; i < 8; ++i)
#pragma unroll
        for (int j = 0; j < 8; ++j) acc[i][j] = 0.0f;

#pragma unroll 4
    for (int k = 0; k < H; ++k) {
        float a[8];
#pragma unroll
        for (int i = 0; i < 8; ++i) a[i] = at[(e0 + i) * 133 + k];
        const float4 b0 = *(const float4*)(W + (size_t)k * H + c0);
        const float4 b1 = *(const float4*)(W + (size_t)k * H + c0 + 4);
        const float bb[8] = {b0.x, b0.y, b0.z, b0.w, b1.x, b1.y, b1.z, b1.w};
#pragma unroll
        for (int i = 0; i < 8; ++i)
#pragma unroll
            for (int j = 0; j < 8; ++j) acc[i][j] = fmaf(a[i], bb[j], acc[i][j]);
    }

#pragma unroll
    for (int ei = 0; ei < 8; ++ei) {
        const int row = abase + e0 + ei;
        float* op = out + (size_t)row * H + c0;
        *(float4*)(op)     = make_float4(acc[ei][0], acc[ei][1], acc[ei][2], acc[ei][3]);
        *(float4*)(op + 4) = make_float4(acc[ei][4], acc[ei][5], acc[ei][6], acc[ei][7]);
    }
}

// ---------------- fused tail: x += tanh(agg@lin2+b2) @ linw + bl ----------------
__global__ __launch_bounds__(128, 2) void k_gemm2x(const float* __restrict__ agg,
                                                   const float* __restrict__ lin2,
                                                   const float* __restrict__ b2,
                                                   const float* __restrict__ linw,
                                                   const float* __restrict__ bl,
                                                   float* __restrict__ x) {
    __shared__ float at[64 * 133];
    const int tid = threadIdx.x;
    const int abase = blockIdx.x * 64;

#pragma unroll
    for (int i = 0; i < 16; ++i) {
        int flat4 = tid + 128 * i;
        int r = flat4 >> 5, k4 = flat4 & 31;
        float4 v = ((const float4*)(agg + (size_t)(abase + r) * H))[k4];
        float* dp = &at[r * 133 + k4 * 4];
        dp[0] = v.x; dp[1] = v.y; dp[2] = v.z; dp[3] = v.w;
    }
    __syncthreads();

    const int eg = tid >> 4, cg = tid & 15;
    const int e0 = eg * 8, c0 = cg * 8;

    float acc[8][8];
#pragma unroll
    for (int i = 0; i < 8; ++i)
#pragma unroll
        for (int j = 0; j < 8; ++j) acc[i][j] = 0.0f;

    // stage 1: agg @ lin2
#pragma unroll 4
    for (int k = 0; k < H; ++k) {
        float a[8];
#pragma unroll
        for (int i = 0; i < 8; ++i) a[i] = at[(e0 + i) * 133 + k];
        const float4 b0 = *(const float4*)(lin2 + (size_t)k * H + c0);
        const float4 b1 = *(const float4*)(lin2 + (size_t)k * H + c0 + 4);
        const float bb[8] = {b0.x, b0.y, b0.z, b0.w, b1.x, b1.y, b1.z, b1.w};
#pragma unroll
        for (int i = 0; i < 8; ++i)
#pragma unroll
            for (int j = 0; j < 8; ++j) acc[i][j] = fmaf(a[i], bb[j], acc[i][j]);
    }

    // + b2, tanh
    {
        const float4 q0 = *(const float4*)(b2 + c0);
        const float4 q1 = *(const float4*)(b2 + c0 + 4);
        const float bv[8] = {q0.x, q0.y, q0.z, q0.w, q1.x, q1.y, q1.z, q1.w};
#pragma unroll
        for (int i = 0; i < 8; ++i)
#pragma unroll
            for (int j = 0; j < 8; ++j) acc[i][j] = fast_tanh(acc[i][j] + bv[j]);
    }

    __syncthreads();   // all stage-1 reads of at done
#pragma unroll
    for (int i = 0; i < 8; ++i)
#pragma unroll
        for (int j = 0; j < 8; ++j) at[(e0 + i) * 133 + c0 + j] = acc[i][j];
    __syncthreads();

    // stage 2: t @ linw
#pragma unroll
    for (int i = 0; i < 8; ++i)
#pragma unroll
        for (int j = 0; j < 8; ++j) acc[i][j] = 0.0f;

#pragma unroll 4
    for (int k = 0; k < H; ++k) {
        float a[8];
#pragma unroll
        for (int i = 0; i < 8; ++i) a[i] = at[(e0 + i) * 133 + k];
        const float4 b0 = *(const float4*)(linw + (size_t)k * H + c0);
        const float4 b1 = *(const float4*)(linw + (size_t)k * H + c0 + 4);
        const float bb[8] = {b0.x, b0.y, b0.z, b0.w, b1.x, b1.y, b1.z, b1.w};
#pragma unroll
        for (int i = 0; i < 8; ++i)
#pragma unroll
            for (int j = 0; j < 8; ++j) acc[i][j] = fmaf(a[i], bb[j], acc[i][j]);
    }

    // epilogue: x += acc + bl
    const float4 q0 = *(const float4*)(bl + c0);
    const float4 q1 = *(const float4*)(bl + c0 + 4);
    const float bv[8] = {q0.x, q0.y, q0.z, q0.w, q1.x, q1.y, q1.z, q1.w};

#pragma unroll
    for (int ei = 0; ei < 8; ++ei) {
        const int row = abase + e0 + ei;
        float* op = x + (size_t)row * H + c0;
        float4 x0 = *(const float4*)(op);
        float4 x1 = *(const float4*)(op + 4);
        *(float4*)(op)     = make_float4(x0.x + acc[ei][0] + bv[0], x0.y + acc[ei][1] + bv[1],
                                         x0.z + acc[ei][2] + bv[2], x0.w + acc[ei][3] + bv[3]);
        *(float4*)(op + 4) = make_float4(x1.x + acc[ei][4] + bv[4], x1.y + acc[ei][5] + bv[5],
                                         x1.z + acc[ei][6] + bv[6], x1.w + acc[ei][7] + bv[7]);
    }
}

// ---------------- K2: edge lookup + gather + register segmented scatter ----------------
// Edges dst-sorted. One wave owns a 64-edge range x 128 cols (2 cols/lane).
// Per edge: W = lerp(tab[i0], tab[i0+1], f); msg = W * h[src]; running per-col
// sums in registers; run boundaries: interior run -> plain store (globally
// exclusive by sortedness), range-boundary run -> atomicAdd. No LDS, no barriers.
__global__ __launch_bounds__(256) void k_edge2(const float* __restrict__ pew,
                                               const int* __restrict__ psrc,
                                               const int* __restrict__ pdst,
                                               const float* __restrict__ tab,
                                               const float* __restrict__ h,
                                               float* __restrict__ agg) {
    const int tid = threadIdx.x;
    const int wave = tid >> 6;
    const int lane = tid & 63;
    const int lo = (blockIdx.x * 4 + wave) * 64;   // this wave's 64-edge range
    const int col0 = lane * 2;

    // per-lane meta for edge lo+lane
    const float d = pew[lo + lane];
    const int sm = psrc[lo + lane];
    const int dm = pdst[lo + lane];
    const float u = d * ((float)(TBL - 1) / CUTF);
    int i0m = (int)u;
    i0m = (i0m > TBL - 2) ? (TBL - 2) : i0m;
    const float fm = u - (float)i0m;
    const unsigned fmb = __float_as_uint(fm);

    float s0 = 0.0f, s1 = 0.0f;
    int cur = __builtin_amdgcn_readlane(dm, 0);
    bool interior = false;

#pragma unroll 4
    for (int e = 0; e < 64; ++e) {
        const int i0 = __builtin_amdgcn_readlane(i0m, e);
        const int src = __builtin_amdgcn_readlane(sm, e);
        const int dn = __builtin_amdgcn_readlane(dm, e);
        const float f = __uint_as_float(__builtin_amdgcn_readlane((int)fmb, e));
        const float2 a0 = *(const float2*)(tab + (size_t)i0 * H + col0);
        const float2 a1 = *(const float2*)(tab + (size_t)(i0 + 1) * H + col0);
        const float2 hv = *(const float2*)(h + (size_t)src * H + col0);
        if (dn != cur) {           // uniform branch (scalar operands)
            float* ap = agg + (size_t)cur * H + col0;
            if (interior) { *(float2*)ap = make_float2(s0, s1); }
            else { atomicAdd(ap, s0); atomicAdd(ap + 1, s1); }
            interior = true;
            cur = dn; s0 = 0.0f; s1 = 0.0f;
        }
        const float w0 = fmaf(f, a1.x - a0.x, a0.x);
        const float w1 = fmaf(f, a1.y - a0.y, a0.y);
        s0 = fmaf(w0, hv.x, s0);
        s1 = fmaf(w1, hv.y, s1);
    }
    // final run touches range end -> always atomic
    float* ap = agg + (size_t)cur * H + col0;
    atomicAdd(ap, s0);
    atomicAdd(ap + 1, s1);
}

// ---------------- K5: energy = tanh(x @ o1 + b1) @ o2 + b2 ----------------
__global__ __launch_bounds__(64) void k_out(const float* __restrict__ x,
                                            const float* __restrict__ o1w,
                                            const float* __restrict__ o1b,
                                            const float* __restrict__ o2w,
                                            const float* __restrict__ o2b,
                                            float* __restrict__ out) {
    __shared__ float xs[64 * 133];
    const int tid = threadIdx.x;
    const int abase = blockIdx.x * 64;

#pragma unroll
    for (int i = 0; i < 32; ++i) {
        int flat4 = tid + 64 * i;
        int r = flat4 >> 5, k4 = flat4 & 31;
        float4 v = ((const float4*)(x + (size_t)(abase + r) * H))[k4];
        float* dp = &xs[r * 133 + k4 * 4];
        dp[0] = v.x; dp[1] = v.y; dp[2] = v.z; dp[3] = v.w;
    }
    __syncthreads();

    float energy = o2b[0];
    for (int j = 0; j < 64; ++j) {
        float a = o1b[j];
#pragma unroll 8
        for (int k = 0; k < H; ++k) a = fmaf(xs[tid * 133 + k], o1w[(size_t)k * 64 + j], a);
        energy = fmaf(fast_tanh(a), o2w[j], energy);
    }
    out[abase + tid] = energy;
}

extern "C" void kernel_launch(void* const* d_in, const int* in_sizes, int n_in,
                              void* d_out, int out_size, void* d_ws, size_t ws_size,
                              hipStream_t stream) {
    const int*   types = (const int*)d_in[0];
    const int*   eidx  = (const int*)d_in[1];
    const float* ew    = (const float*)d_in[2];
    const float* emb   = (const float*)d_in[3];
    const float* lin1  = (const float*)d_in[4];
    const float* fw1   = (const float*)d_in[5];
    const float* fb1   = (const float*)d_in[6];
    const float* fw2   = (const float*)d_in[7];
    const float* fb2   = (const float*)d_in[8];
    const float* lin2  = (const float*)d_in[9];
    const float* lin2b = (const float*)d_in[10];
    const float* linw  = (const float*)d_in[11];
    const float* linb  = (const float*)d_in[12];
    const float* o1w   = (const float*)d_in[13];
    const float* o1b   = (const float*)d_in[14];
    const float* o2w   = (const float*)d_in[15];
    const float* o2b   = (const float*)d_in[16];
    float* out = (float*)d_out;

    // ws carve
    float* x      = (float*)d_ws;                       // N*H
    float* h      = x + (size_t)N_ATOMS * H;            // N*H
    float* agg    = h + (size_t)N_ATOMS * H;            // N*H
    float* tab    = agg + (size_t)N_ATOMS * H;          // NBLK*TBL*H
    int*   cnt    = (int*)(tab + (size_t)NBLK * TBL * H);  // N
    int*   cursor = cnt + N_ATOMS;                      // N
    int*   psrc   = cursor + N_ATOMS;                   // E
    int*   pdst   = psrc + E_EDGES;                     // E
    float* pew    = (float*)(pdst + E_EDGES);           // E

    // ---- build dst-sorted edge arrays ----
    hipMemsetAsync(cnt, 0, N_ATOMS * sizeof(int), stream);
    k_count<<<E_EDGES / 256, 256, 0, stream>>>(eidx, cnt);
    k_scan<<<1, 1024, 0, stream>>>(cnt, cursor);
    k_fill<<<E_EDGES / 256, 256, 0, stream>>>(eidx, ew, cursor, pew, psrc, pdst);

    // ---- embed + filter tables (independent of x) ----
    k_embed<<<(N_ATOMS * H / 4) / 256, 256, 0, stream>>>(types, emb, x);
    k_table<<<dim3(TBL / 128, NBLK), 256, 0, stream>>>(fw1, fb1, fw2, fb2, tab);

    for (int b = 0; b < NBLK; ++b) {
        // h = x @ lin1[b]
        k_gemm_nh<0><<<N_ATOMS / 64, 128, 0, stream>>>(x, lin1 + (size_t)b * H * H, h);
        // agg = 0
        hipMemsetAsync(agg, 0, (size_t)N_ATOMS * H * sizeof(float), stream);
        // lookup + gather + sorted register scatter
        k_edge2<<<E_EDGES / 256, 256, 0, stream>>>(pew, psrc, pdst,
                                                   tab + (size_t)b * TBL * H, h, agg);
        // x += tanh(agg @ lin2[b] + b2) @ linw[b] + bl
        k_gemm2x<<<N_ATOMS / 64, 128, 0, stream>>>(agg, lin2 + (size_t)b * H * H,
                                                   lin2b + (size_t)b * H,
                                                   linw + (size_t)b * H * H,
                                                   linb + (size_t)b * H, x);
    }

    k_out<<<N_ATOMS / 64, 64, 0, stream>>>(x, o1w, o1b, o2w, o2b, out);
}

// Round 4
// 853.336 us; speedup vs baseline: 8.7224x; 1.0511x over previous
//
#include <hip/hip_runtime.h>
#include <math.h>

#define N_ATOMS 40000
#define E_EDGES 640000
#define H 128
#define RBF 64
#define NBLK 3
#define CUTF 5.0f
#define TBL 8192   // filter lookup table entries per interaction block

// stable fast tanh: exp-based, saturates correctly at +/-inf
__device__ __forceinline__ float fast_tanh(float x) {
    return 1.0f - 2.0f / (1.0f + __expf(2.0f * x));
}

// ---------------- K0: x = emb[atom_types] ----------------
__global__ __launch_bounds__(256) void k_embed(const int* __restrict__ types,
                                               const float* __restrict__ emb,
                                               float* __restrict__ x) {
    int flat4 = blockIdx.x * 256 + threadIdx.x;  // over N*H/4
    int i = flat4 >> 5;   // 32 float4 per row
    int c4 = flat4 & 31;
    int t = types[i];
    const float4* e4 = (const float4*)(emb + (size_t)t * H);
    ((float4*)(x + (size_t)i * H))[c4] = e4[c4];
}

// ---------------- CSR build ----------------
__global__ __launch_bounds__(256) void k_count(const int* __restrict__ eidx,
                                               int* __restrict__ cnt) {
    int e = blockIdx.x * 256 + threadIdx.x;
    atomicAdd(&cnt[eidx[E_EDGES + e]], 1);
}

// hierarchical exclusive scan of cnt[N_ATOMS]: A) per-1024-block sums
__global__ __launch_bounds__(1024) void k_scanA(const int* __restrict__ cnt,
                                                int* __restrict__ bsum) {
    __shared__ int ws[16];
    const int tid = threadIdx.x, lane = tid & 63, wid = tid >> 6;
    int idx = blockIdx.x * 1024 + tid;
    int v = (idx < N_ATOMS) ? cnt[idx] : 0;
#pragma unroll
    for (int off = 32; off; off >>= 1) v += __shfl_xor(v, off, 64);
    if (lane == 0) ws[wid] = v;
    __syncthreads();
    if (tid == 0) {
        int s = 0;
#pragma unroll
        for (int w = 0; w < 16; ++w) s += ws[w];
        bsum[blockIdx.x] = s;
    }
}

// B) exclusive scan of the 40 block sums (one wave)
__global__ __launch_bounds__(64) void k_scanB(const int* __restrict__ bsum,
                                              int* __restrict__ boff) {
    const int lane = threadIdx.x;
    int v = (lane < 40) ? bsum[lane] : 0;
    int inc = v;
#pragma unroll
    for (int off = 1; off < 64; off <<= 1) {
        int t = __shfl_up(inc, off, 64);
        if (lane >= off) inc += t;
    }
    if (lane < 40) boff[lane] = inc - v;
}

// C) per-block exclusive scan + block offset -> cursor & row_start
__global__ __launch_bounds__(1024) void k_scanC(const int* __restrict__ cnt,
                                                const int* __restrict__ boff,
                                                int* __restrict__ cursor,
                                                int* __restrict__ rstart) {
    __shared__ int wsum[16];
    __shared__ int woff[16];
    const int tid = threadIdx.x, lane = tid & 63, wid = tid >> 6;
    int idx = blockIdx.x * 1024 + tid;
    int v = (idx < N_ATOMS) ? cnt[idx] : 0;
    int inc = v;
#pragma unroll
    for (int off = 1; off < 64; off <<= 1) {
        int t = __shfl_up(inc, off, 64);
        if (lane >= off) inc += t;
    }
    if (lane == 63) wsum[wid] = inc;
    __syncthreads();
    if (tid == 0) {
        int acc = 0;
#pragma unroll
        for (int w = 0; w < 16; ++w) { woff[w] = acc; acc += wsum[w]; }
    }
    __syncthreads();
    if (idx < N_ATOMS) {
        int ex = boff[blockIdx.x] + woff[wid] + inc - v;
        cursor[idx] = ex;
        rstart[idx] = ex;
    }
}

// fill: pmeta[pos] = {src, float_bits(u)} with u = d*(TBL-1)/CUT (dst-sorted)
__global__ __launch_bounds__(256) void k_fill(const int* __restrict__ eidx,
                                              const float* __restrict__ ew,
                                              int* __restrict__ cursor,
                                              int2* __restrict__ pmeta) {
    int e = blockIdx.x * 256 + threadIdx.x;
    int dd = eidx[E_EDGES + e];
    int pos = atomicAdd(&cursor[dd], 1);
    float u = ew[e] * ((float)(TBL - 1) / CUTF);
    pmeta[pos] = make_int2(eidx[e], __float_as_int(u));
}

// ---------------- K1: filter table build (interleaved pairs) ----------------
// tabI[b][m][c] = {Wc(m), Wc(m+1)} so a lerp needs rows m only.
__global__ __launch_bounds__(256, 2) void k_table(const float* __restrict__ fw1all,
                                                  const float* __restrict__ fb1all,
                                                  const float* __restrict__ fw2all,
                                                  const float* __restrict__ fb2all,
                                                  float* __restrict__ tabI) {
    const int b = blockIdx.y;
    const float* fw1 = fw1all + (size_t)b * RBF * H;
    const float* fb1 = fb1all + (size_t)b * H;
    const float* fw2 = fw2all + (size_t)b * H * H;
    const float* fb2 = fb2all + (size_t)b * H;
    float* tabB = tabI + (size_t)b * TBL * H * 2;

    __shared__ float tile[128 * 133];
    const int tid = threadIdx.x;
    const int mbase = blockIdx.x * 128;
    const float DSTEP = CUTF / (float)(TBL - 1);

    {
        const int e = tid & 127;
        const int k0 = (tid >> 7) * 32;
        const float d = (float)(mbase + e) * DSTEP;
        const float DELTA = CUTF / 63.0f;
        const float COEFF = -0.5f / (DELTA * DELTA);
#pragma unroll
        for (int k = k0; k < k0 + 32; ++k) {
            float diff = d - (float)k * DELTA;
            tile[e * 133 + k] = __expf(COEFF * diff * diff);
        }
    }
    __syncthreads();

    const int eg = tid >> 4, cg = tid & 15;
    const int e0 = eg * 8, c0 = cg * 8;

    float acc[8][8];
#pragma unroll
    for (int i = 0; i < 8; ++i)
#pragma unroll
        for (int j = 0; j < 8; ++j) acc[i][j] = 0.0f;

#pragma unroll 4
    for (int k = 0; k < RBF; ++k) {
        float a[8];
#pragma unroll
        for (int i = 0; i < 8; ++i) a[i] = tile[(e0 + i) * 133 + k];
        const float4 b0 = *(const float4*)(fw1 + (size_t)k * H + c0);
        const float4 b1 = *(const float4*)(fw1 + (size_t)k * H + c0 + 4);
        const float bb[8] = {b0.x, b0.y, b0.z, b0.w, b1.x, b1.y, b1.z, b1.w};
#pragma unroll
        for (int i = 0; i < 8; ++i)
#pragma unroll
            for (int j = 0; j < 8; ++j) acc[i][j] = fmaf(a[i], bb[j], acc[i][j]);
    }

    {
        const float4 q0 = *(const float4*)(fb1 + c0);
        const float4 q1 = *(const float4*)(fb1 + c0 + 4);
        const float bv[8] = {q0.x, q0.y, q0.z, q0.w, q1.x, q1.y, q1.z, q1.w};
#pragma unroll
        for (int i = 0; i < 8; ++i)
#pragma unroll
            for (int j = 0; j < 8; ++j) acc[i][j] = fast_tanh(acc[i][j] + bv[j]);
    }

    __syncthreads();
#pragma unroll
    for (int i = 0; i < 8; ++i)
#pragma unroll
        for (int j = 0; j < 8; ++j) tile[(e0 + i) * 133 + c0 + j] = acc[i][j];
    __syncthreads();

#pragma unroll
    for (int i = 0; i < 8; ++i)
#pragma unroll
        for (int j = 0; j < 8; ++j) acc[i][j] = 0.0f;

#pragma unroll 4
    for (int k = 0; k < H; ++k) {
        float a[8];
#pragma unroll
        for (int i = 0; i < 8; ++i) a[i] = tile[(e0 + i) * 133 + k];
        const float4 b0 = *(const float4*)(fw2 + (size_t)k * H + c0);
        const float4 b1 = *(const float4*)(fw2 + (size_t)k * H + c0 + 4);
        const float bb[8] = {b0.x, b0.y, b0.z, b0.w, b1.x, b1.y, b1.z, b1.w};
#pragma unroll
        for (int i = 0; i < 8; ++i)
#pragma unroll
            for (int j = 0; j < 8; ++j) acc[i][j] = fmaf(a[i], bb[j], acc[i][j]);
    }

    const float4 q0 = *(const float4*)(fb2 + c0);
    const float4 q1 = *(const float4*)(fb2 + c0 + 4);
    const float bv[8] = {q0.x, q0.y, q0.z, q0.w, q1.x, q1.y, q1.z, q1.w};

#pragma unroll
    for (int ei = 0; ei < 8; ++ei) {
        const int m = mbase + e0 + ei;
        const float d = (float)m * DSTEP;
        float c = 0.5f * (cosf(0.6283185307179586f * d) + 1.0f);
        c = (d < CUTF) ? c : 0.0f;
#pragma unroll
        for (int j = 0; j < 8; ++j) {
            float r = (acc[ei][j] + bv[j]) * c;
            const int col = c0 + j;
            tabB[((size_t)m * H + col) * 2] = r;              // entry m, .x
            if (m > 0)
                tabB[((size_t)(m - 1) * H + col) * 2 + 1] = r; // entry m-1, .y
        }
    }
}

// ---------------- GEMM (N x H) @ (H x H): out = A@W (lin1) ----------------
__global__ __launch_bounds__(128, 2) void k_gemm_nh(const float* __restrict__ A,
                                                    const float* __restrict__ W,
                                                    float* __restrict__ out) {
    __shared__ float at[64 * 133];
    const int tid = threadIdx.x;
    const int abase = blockIdx.x * 64;

#pragma unroll
    for (int i = 0; i < 16; ++i) {
        int flat4 = tid + 128 * i;
        int r = flat4 >> 5, k4 = flat4 & 31;
        float4 v = ((const float4*)(A + (size_t)(abase + r) * H))[k4];
        float* dp = &at[r * 133 + k4 * 4];
        dp[0] = v.x; dp[1] = v.y; dp[2] = v.z; dp[3] = v.w;
    }
    __syncthreads();

    const int eg = tid >> 4, cg = tid & 15;
    const int e0 = eg * 8, c0 = cg * 8;

    float acc[8][8];
#pragma unroll
    for (int i = 0; i < 8; ++i)
#pragma unroll
        for (int j = 0; j < 8; ++j) acc[i][j] = 0.0f;

#pragma unroll 4
    for (int k = 0; k < H; ++k) {
        float a[8];
#pragma unroll
        for (int i = 0; i < 8; ++i) a[i] = at[(e0 + i) * 133 + k];
        const float4 b0 = *(const float4*)(W + (size_t)k * H + c0);
        const float4 b1 = *(const float4*)(W + (size_t)k * H + c0 + 4);
        const float bb[8] = {b0.x, b0.y, b0.z, b0.w, b1.x, b1.y, b1.z, b1.w};
#pragma unroll
        for (int i = 0; i < 8; ++i)
#pragma unroll
            for (int j = 0; j < 8; ++j) acc[i][j] = fmaf(a[i], bb[j], acc[i][j]);
    }

#pragma unroll
    for (int ei = 0; ei < 8; ++ei) {
        const int row = abase + e0 + ei;
        float* op = out + (size_t)row * H + c0;
        *(float4*)(op)     = make_float4(acc[ei][0], acc[ei][1], acc[ei][2], acc[ei][3]);
        *(float4*)(op + 4) = make_float4(acc[ei][4], acc[ei][5], acc[ei][6], acc[ei][7]);
    }
}

// ---------------- fused tail: x += tanh(agg@lin2+b2) @ linw + bl ----------------
__global__ __launch_bounds__(128, 2) void k_gemm2x(const float* __restrict__ agg,
                                                   const float* __restrict__ lin2,
                                                   const float* __restrict__ b2,
                                                   const float* __restrict__ linw,
                                                   const float* __restrict__ bl,
                                                   float* __restrict__ x) {
    __shared__ float at[64 * 133];
    const int tid = threadIdx.x;
    const int abase = blockIdx.x * 64;

#pragma unroll
    for (int i = 0; i < 16; ++i) {
        int flat4 = tid + 128 * i;
        int r = flat4 >> 5, k4 = flat4 & 31;
        float4 v = ((const float4*)(agg + (size_t)(abase + r) * H))[k4];
        float* dp = &at[r * 133 + k4 * 4];
        dp[0] = v.x; dp[1] = v.y; dp[2] = v.z; dp[3] = v.w;
    }
    __syncthreads();

    const int eg = tid >> 4, cg = tid & 15;
    const int e0 = eg * 8, c0 = cg * 8;

    float acc[8][8];
#pragma unroll
    for (int i = 0; i < 8; ++i)
#pragma unroll
        for (int j = 0; j < 8; ++j) acc[i][j] = 0.0f;

#pragma unroll 4
    for (int k = 0; k < H; ++k) {
        float a[8];
#pragma unroll
        for (int i = 0; i < 8; ++i) a[i] = at[(e0 + i) * 133 + k];
        const float4 b0 = *(const float4*)(lin2 + (size_t)k * H + c0);
        const float4 b1 = *(const float4*)(lin2 + (size_t)k * H + c0 + 4);
        const float bb[8] = {b0.x, b0.y, b0.z, b0.w, b1.x, b1.y, b1.z, b1.w};
#pragma unroll
        for (int i = 0; i < 8; ++i)
#pragma unroll
            for (int j = 0; j < 8; ++j) acc[i][j] = fmaf(a[i], bb[j], acc[i][j]);
    }

    {
        const float4 q0 = *(const float4*)(b2 + c0);
        const float4 q1 = *(const float4*)(b2 + c0 + 4);
        const float bv[8] = {q0.x, q0.y, q0.z, q0.w, q1.x, q1.y, q1.z, q1.w};
#pragma unroll
        for (int i = 0; i < 8; ++i)
#pragma unroll
            for (int j = 0; j < 8; ++j) acc[i][j] = fast_tanh(acc[i][j] + bv[j]);
    }

    __syncthreads();
#pragma unroll
    for (int i = 0; i < 8; ++i)
#pragma unroll
        for (int j = 0; j < 8; ++j) at[(e0 + i) * 133 + c0 + j] = acc[i][j];
    __syncthreads();

#pragma unroll
    for (int i = 0; i < 8; ++i)
#pragma unroll
        for (int j = 0; j < 8; ++j) acc[i][j] = 0.0f;

#pragma unroll 4
    for (int k = 0; k < H; ++k) {
        float a[8];
#pragma unroll
        for (int i = 0; i < 8; ++i) a[i] = at[(e0 + i) * 133 + k];
        const float4 b0 = *(const float4*)(linw + (size_t)k * H + c0);
        const float4 b1 = *(const float4*)(linw + (size_t)k * H + c0 + 4);
        const float bb[8] = {b0.x, b0.y, b0.z, b0.w, b1.x, b1.y, b1.z, b1.w};
#pragma unroll
        for (int i = 0; i < 8; ++i)
#pragma unroll
            for (int j = 0; j < 8; ++j) acc[i][j] = fmaf(a[i], bb[j], acc[i][j]);
    }

    const float4 q0 = *(const float4*)(bl + c0);
    const float4 q1 = *(const float4*)(bl + c0 + 4);
    const float bv[8] = {q0.x, q0.y, q0.z, q0.w, q1.x, q1.y, q1.z, q1.w};

#pragma unroll
    for (int ei = 0; ei < 8; ++ei) {
        const int row = abase + e0 + ei;
        float* op = x + (size_t)row * H + c0;
        float4 x0 = *(const float4*)(op);
        float4 x1 = *(const float4*)(op + 4);
        *(float4*)(op)     = make_float4(x0.x + acc[ei][0] + bv[0], x0.y + acc[ei][1] + bv[1],
                                         x0.z + acc[ei][2] + bv[2], x0.w + acc[ei][3] + bv[3]);
        *(float4*)(op + 4) = make_float4(x1.x + acc[ei][4] + bv[4], x1.y + acc[ei][5] + bv[5],
                                         x1.z + acc[ei][6] + bv[6], x1.w + acc[ei][7] + bv[7]);
    }
}

// ---------------- K2: atom-centric gather-aggregate (no atomics) ----------------
// one wave per dst atom: agg[a] = sum_{e in row(a)} lerp(tabI, u_e) * h[src_e]
__global__ __launch_bounds__(256) void k_edge3(const int* __restrict__ rstart,
                                               const int* __restrict__ rend,
                                               const int2* __restrict__ pmeta,
                                               const float* __restrict__ tabI,
                                               const float* __restrict__ h,
                                               float* __restrict__ agg) {
    const int wave = threadIdx.x >> 6;
    const int lane = threadIdx.x & 63;
    const int a = blockIdx.x * 4 + wave;
    const int col0 = lane * 2;

    const int s = rstart[a];
    const int e_end = rend[a];

    float s0 = 0.0f, s1 = 0.0f;
    for (int e = s; e < e_end; ++e) {
        const int2 m = pmeta[e];                 // broadcast 8B load
        const float u = __int_as_float(m.y);
        int i0 = (int)u;
        i0 = (i0 > TBL - 2) ? (TBL - 2) : i0;
        const float f = u - (float)i0;
        // interleaved pair {W[i0][c], W[i0+1][c]} as float4 covering 2 cols
        const float4 t4 = *(const float4*)(tabI + ((size_t)i0 * H + col0) * 2);
        const float2 hv = *(const float2*)(h + (size_t)m.x * H + col0);
        s0 = fmaf(fmaf(f, t4.y - t4.x, t4.x), hv.x, s0);
        s1 = fmaf(fmaf(f, t4.w - t4.z, t4.z), hv.y, s1);
    }
    *(float2*)(agg + (size_t)a * H + col0) = make_float2(s0, s1);
}

// ---------------- K5: energy, tiled: 64 atoms x 64 cols per 256-thread block ----------------
__global__ __launch_bounds__(256) void k_out(const float* __restrict__ x,
                                             const float* __restrict__ o1w,
                                             const float* __restrict__ o1b,
                                             const float* __restrict__ o2w,
                                             const float* __restrict__ o2b,
                                             float* __restrict__ out) {
    __shared__ float xs[64 * 132];
    const int tid = threadIdx.x;
    const int abase = blockIdx.x * 64;

#pragma unroll
    for (int i = 0; i < 8; ++i) {
        int flat4 = tid + 256 * i;
        int r = flat4 >> 5, k4 = flat4 & 31;
        float4 v = ((const float4*)(x + (size_t)(abase + r) * H))[k4];
        float* dp = &xs[r * 132 + k4 * 4];
        dp[0] = v.x; dp[1] = v.y; dp[2] = v.z; dp[3] = v.w;
    }
    __syncthreads();

    const int eg = tid >> 4, cg = tid & 15;   // eg: 16 row groups, cg: 16 col groups
    const int r0 = eg * 4, c0 = cg * 4;

    float acc[4][4];
#pragma unroll
    for (int i = 0; i < 4; ++i)
#pragma unroll
        for (int j = 0; j < 4; ++j) acc[i][j] = 0.0f;

#pragma unroll 4
    for (int k = 0; k < H; ++k) {
        float a[4];
#pragma unroll
        for (int i = 0; i < 4; ++i) a[i] = xs[(r0 + i) * 132 + k];
        const float4 b = *(const float4*)(o1w + (size_t)k * 64 + c0);
        const float bb[4] = {b.x, b.y, b.z, b.w};
#pragma unroll
        for (int i = 0; i < 4; ++i)
#pragma unroll
            for (int j = 0; j < 4; ++j) acc[i][j] = fmaf(a[i], bb[j], acc[i][j]);
    }

    // p[r] = sum_c tanh(acc + o1b) * o2w
    const float4 ob = *(const float4*)(o1b + c0);
    const float4 ow = *(const float4*)(o2w + c0);
    const float obv[4] = {ob.x, ob.y, ob.z, ob.w};
    const float owv[4] = {ow.x, ow.y, ow.z, ow.w};
    float p[4];
#pragma unroll
    for (int i = 0; i < 4; ++i) {
        float s = 0.0f;
#pragma unroll
        for (int j = 0; j < 4; ++j) s = fmaf(fast_tanh(acc[i][j] + obv[j]), owv[j], s);
        p[i] = s;
    }
    // reduce across the 16 cg lanes (contiguous within wave)
#pragma unroll
    for (int off = 1; off < 16; off <<= 1) {
#pragma unroll
        for (int i = 0; i < 4; ++i) p[i] += __shfl_xor(p[i], off, 64);
    }
    if (cg == 0) {
        const float b2 = o2b[0];
#pragma unroll
        for (int i = 0; i < 4; ++i) out[abase + r0 + i] = p[i] + b2;
    }
}

extern "C" void kernel_launch(void* const* d_in, const int* in_sizes, int n_in,
                              void* d_out, int out_size, void* d_ws, size_t ws_size,
                              hipStream_t stream) {
    const int*   types = (const int*)d_in[0];
    const int*   eidx  = (const int*)d_in[1];
    const float* ew    = (const float*)d_in[2];
    const float* emb   = (const float*)d_in[3];
    const float* lin1  = (const float*)d_in[4];
    const float* fw1   = (const float*)d_in[5];
    const float* fb1   = (const float*)d_in[6];
    const float* fw2   = (const float*)d_in[7];
    const float* fb2   = (const float*)d_in[8];
    const float* lin2  = (const float*)d_in[9];
    const float* lin2b = (const float*)d_in[10];
    const float* linw  = (const float*)d_in[11];
    const float* linb  = (const float*)d_in[12];
    const float* o1w   = (const float*)d_in[13];
    const float* o1b   = (const float*)d_in[14];
    const float* o2w   = (const float*)d_in[15];
    const float* o2b   = (const float*)d_in[16];
    float* out = (float*)d_out;

    // ws carve
    float* x      = (float*)d_ws;                            // N*H
    float* h      = x + (size_t)N_ATOMS * H;                 // N*H
    float* agg    = h + (size_t)N_ATOMS * H;                 // N*H
    float* tabI   = agg + (size_t)N_ATOMS * H;               // NBLK*TBL*H*2
    int*   cnt    = (int*)(tabI + (size_t)NBLK * TBL * H * 2);  // N
    int*   cursor = cnt + N_ATOMS;                           // N
    int*   rstart = cursor + N_ATOMS;                        // N
    int*   bsum   = rstart + N_ATOMS;                        // 40
    int*   boff   = bsum + 64;                               // 40
    int2*  pmeta  = (int2*)(boff + 64);                      // E

    // ---- CSR build ----
    hipMemsetAsync(cnt, 0, N_ATOMS * sizeof(int), stream);
    k_count<<<E_EDGES / 256, 256, 0, stream>>>(eidx, cnt);
    k_scanA<<<40, 1024, 0, stream>>>(cnt, bsum);
    k_scanB<<<1, 64, 0, stream>>>(bsum, boff);
    k_scanC<<<40, 1024, 0, stream>>>(cnt, boff, cursor, rstart);
    k_fill<<<E_EDGES / 256, 256, 0, stream>>>(eidx, ew, cursor, pmeta);
    // after k_fill, cursor[a] == row end of atom a

    // ---- embed + filter tables ----
    k_embed<<<(N_ATOMS * H / 4) / 256, 256, 0, stream>>>(types, emb, x);
    k_table<<<dim3(TBL / 128, NBLK), 256, 0, stream>>>(fw1, fb1, fw2, fb2, tabI);

    for (int b = 0; b < NBLK; ++b) {
        k_gemm_nh<<<N_ATOMS / 64, 128, 0, stream>>>(x, lin1 + (size_t)b * H * H, h);
        k_edge3<<<N_ATOMS / 4, 256, 0, stream>>>(rstart, cursor, pmeta,
                                                 tabI + (size_t)b * TBL * H * 2, h, agg);
        k_gemm2x<<<N_ATOMS / 64, 128, 0, stream>>>(agg, lin2 + (size_t)b * H * H,
                                                   lin2b + (size_t)b * H,
                                                   linw + (size_t)b * H * H,
                                                   linb + (size_t)b * H, x);
    }

    k_out<<<N_ATOMS / 64, 256, 0, stream>>>(x, o1w, o1b, o2w, o2b, out);
}

// Round 5
// 665.044 us; speedup vs baseline: 11.1919x; 1.2831x over previous
//
#include <hip/hip_runtime.h>
#include <math.h>

#define N_ATOMS 40000
#define E_EDGES 640000
#define H 128
#define RBF 64
#define NBLK 3
#define CUTF 5.0f
#define TBL 4096   // filter lookup table entries per block (2 MB -> L2-resident)

// stable fast tanh: exp-based, saturates correctly at +/-inf
__device__ __forceinline__ float fast_tanh(float x) {
    return 1.0f - 2.0f / (1.0f + __expf(2.0f * x));
}

// ---------------- K0: x = emb[atom_types] ----------------
__global__ __launch_bounds__(256) void k_embed(const int* __restrict__ types,
                                               const float* __restrict__ emb,
                                               float* __restrict__ x) {
    int flat4 = blockIdx.x * 256 + threadIdx.x;  // over N*H/4
    int i = flat4 >> 5;
    int c4 = flat4 & 31;
    int t = types[i];
    const float4* e4 = (const float4*)(emb + (size_t)t * H);
    ((float4*)(x + (size_t)i * H))[c4] = e4[c4];
}

// ---------------- CSR build ----------------
__global__ __launch_bounds__(256) void k_count(const int* __restrict__ eidx,
                                               int* __restrict__ cnt) {
    int e = blockIdx.x * 256 + threadIdx.x;
    atomicAdd(&cnt[eidx[E_EDGES + e]], 1);
}

__global__ __launch_bounds__(1024) void k_scanA(const int* __restrict__ cnt,
                                                int* __restrict__ bsum) {
    __shared__ int ws[16];
    const int tid = threadIdx.x, lane = tid & 63, wid = tid >> 6;
    int idx = blockIdx.x * 1024 + tid;
    int v = (idx < N_ATOMS) ? cnt[idx] : 0;
#pragma unroll
    for (int off = 32; off; off >>= 1) v += __shfl_xor(v, off, 64);
    if (lane == 0) ws[wid] = v;
    __syncthreads();
    if (tid == 0) {
        int s = 0;
#pragma unroll
        for (int w = 0; w < 16; ++w) s += ws[w];
        bsum[blockIdx.x] = s;
    }
}

__global__ __launch_bounds__(64) void k_scanB(const int* __restrict__ bsum,
                                              int* __restrict__ boff) {
    const int lane = threadIdx.x;
    int v = (lane < 40) ? bsum[lane] : 0;
    int inc = v;
#pragma unroll
    for (int off = 1; off < 64; off <<= 1) {
        int t = __shfl_up(inc, off, 64);
        if (lane >= off) inc += t;
    }
    if (lane < 40) boff[lane] = inc - v;
}

__global__ __launch_bounds__(1024) void k_scanC(const int* __restrict__ cnt,
                                                const int* __restrict__ boff,
                                                int* __restrict__ cursor,
                                                int* __restrict__ rstart) {
    __shared__ int wsum[16];
    __shared__ int woff[16];
    const int tid = threadIdx.x, lane = tid & 63, wid = tid >> 6;
    int idx = blockIdx.x * 1024 + tid;
    int v = (idx < N_ATOMS) ? cnt[idx] : 0;
    int inc = v;
#pragma unroll
    for (int off = 1; off < 64; off <<= 1) {
        int t = __shfl_up(inc, off, 64);
        if (lane >= off) inc += t;
    }
    if (lane == 63) wsum[wid] = inc;
    __syncthreads();
    if (tid == 0) {
        int acc = 0;
#pragma unroll
        for (int w = 0; w < 16; ++w) { woff[w] = acc; acc += wsum[w]; }
    }
    __syncthreads();
    if (idx < N_ATOMS) {
        int ex = boff[blockIdx.x] + woff[wid] + inc - v;
        cursor[idx] = ex;
        rstart[idx] = ex;
    }
}

// fill: pmeta[pos] = {src, float_bits(u)}, u = d*(TBL-1)/CUT (dst-sorted)
__global__ __launch_bounds__(256) void k_fill(const int* __restrict__ eidx,
                                              const float* __restrict__ ew,
                                              int* __restrict__ cursor,
                                              int2* __restrict__ pmeta) {
    int e = blockIdx.x * 256 + threadIdx.x;
    int dd = eidx[E_EDGES + e];
    int pos = atomicAdd(&cursor[dd], 1);
    float u = ew[e] * ((float)(TBL - 1) / CUTF);
    pmeta[pos] = make_int2(eidx[e], __float_as_int(u));
}

// ---------------- K1: filter table build (plain rows) ----------------
// tab[b][m][j] = (tanh(rbf(d_m)@fw1+b1) @ fw2 + b2)[j] * C(d_m), d_m = m*CUT/(TBL-1)
__global__ __launch_bounds__(256, 2) void k_table(const float* __restrict__ fw1all,
                                                  const float* __restrict__ fb1all,
                                                  const float* __restrict__ fw2all,
                                                  const float* __restrict__ fb2all,
                                                  float* __restrict__ tab) {
    const int b = blockIdx.y;
    const float* fw1 = fw1all + (size_t)b * RBF * H;
    const float* fb1 = fb1all + (size_t)b * H;
    const float* fw2 = fw2all + (size_t)b * H * H;
    const float* fb2 = fb2all + (size_t)b * H;
    float* tabB = tab + (size_t)b * TBL * H;

    __shared__ float tile[128 * 133];
    const int tid = threadIdx.x;
    const int mbase = blockIdx.x * 128;
    const float DSTEP = CUTF / (float)(TBL - 1);

    {
        const int e = tid & 127;
        const int k0 = (tid >> 7) * 32;
        const float d = (float)(mbase + e) * DSTEP;
        const float DELTA = CUTF / 63.0f;
        const float COEFF = -0.5f / (DELTA * DELTA);
#pragma unroll
        for (int k = k0; k < k0 + 32; ++k) {
            float diff = d - (float)k * DELTA;
            tile[e * 133 + k] = __expf(COEFF * diff * diff);
        }
    }
    __syncthreads();

    const int eg = tid >> 4, cg = tid & 15;
    const int e0 = eg * 8, c0 = cg * 8;

    float acc[8][8];
#pragma unroll
    for (int i = 0; i < 8; ++i)
#pragma unroll
        for (int j = 0; j < 8; ++j) acc[i][j] = 0.0f;

#pragma unroll 4
    for (int k = 0; k < RBF; ++k) {
        float a[8];
#pragma unroll
        for (int i = 0; i < 8; ++i) a[i] = tile[(e0 + i) * 133 + k];
        const float4 b0 = *(const float4*)(fw1 + (size_t)k * H + c0);
        const float4 b1 = *(const float4*)(fw1 + (size_t)k * H + c0 + 4);
        const float bb[8] = {b0.x, b0.y, b0.z, b0.w, b1.x, b1.y, b1.z, b1.w};
#pragma unroll
        for (int i = 0; i < 8; ++i)
#pragma unroll
            for (int j = 0; j < 8; ++j) acc[i][j] = fmaf(a[i], bb[j], acc[i][j]);
    }

    {
        const float4 q0 = *(const float4*)(fb1 + c0);
        const float4 q1 = *(const float4*)(fb1 + c0 + 4);
        const float bv[8] = {q0.x, q0.y, q0.z, q0.w, q1.x, q1.y, q1.z, q1.w};
#pragma unroll
        for (int i = 0; i < 8; ++i)
#pragma unroll
            for (int j = 0; j < 8; ++j) acc[i][j] = fast_tanh(acc[i][j] + bv[j]);
    }

    __syncthreads();
#pragma unroll
    for (int i = 0; i < 8; ++i)
#pragma unroll
        for (int j = 0; j < 8; ++j) tile[(e0 + i) * 133 + c0 + j] = acc[i][j];
    __syncthreads();

#pragma unroll
    for (int i = 0; i < 8; ++i)
#pragma unroll
        for (int j = 0; j < 8; ++j) acc[i][j] = 0.0f;

#pragma unroll 4
    for (int k = 0; k < H; ++k) {
        float a[8];
#pragma unroll
        for (int i = 0; i < 8; ++i) a[i] = tile[(e0 + i) * 133 + k];
        const float4 b0 = *(const float4*)(fw2 + (size_t)k * H + c0);
        const float4 b1 = *(const float4*)(fw2 + (size_t)k * H + c0 + 4);
        const float bb[8] = {b0.x, b0.y, b0.z, b0.w, b1.x, b1.y, b1.z, b1.w};
#pragma unroll
        for (int i = 0; i < 8; ++i)
#pragma unroll
            for (int j = 0; j < 8; ++j) acc[i][j] = fmaf(a[i], bb[j], acc[i][j]);
    }

    const float4 q0 = *(const float4*)(fb2 + c0);
    const float4 q1 = *(const float4*)(fb2 + c0 + 4);
    const float bv[8] = {q0.x, q0.y, q0.z, q0.w, q1.x, q1.y, q1.z, q1.w};

#pragma unroll
    for (int ei = 0; ei < 8; ++ei) {
        const int m = mbase + e0 + ei;
        const float d = (float)m * DSTEP;
        float c = 0.5f * (cosf(0.6283185307179586f * d) + 1.0f);
        c = (d < CUTF) ? c : 0.0f;
        float* op = tabB + (size_t)m * H + c0;
        float r[8];
#pragma unroll
        for (int j = 0; j < 8; ++j) r[j] = (acc[ei][j] + bv[j]) * c;
        *(float4*)(op)     = make_float4(r[0], r[1], r[2], r[3]);
        *(float4*)(op + 4) = make_float4(r[4], r[5], r[6], r[7]);
    }
}

// ---------------- GEMM (N x H) @ (H x H): out = A@W (lin1, b=0 only) ----------------
__global__ __launch_bounds__(128, 2) void k_gemm_nh(const float* __restrict__ A,
                                                    const float* __restrict__ W,
                                                    float* __restrict__ out) {
    __shared__ float at[64 * 133];
    const int tid = threadIdx.x;
    const int abase = blockIdx.x * 64;

#pragma unroll
    for (int i = 0; i < 16; ++i) {
        int flat4 = tid + 128 * i;
        int r = flat4 >> 5, k4 = flat4 & 31;
        float4 v = ((const float4*)(A + (size_t)(abase + r) * H))[k4];
        float* dp = &at[r * 133 + k4 * 4];
        dp[0] = v.x; dp[1] = v.y; dp[2] = v.z; dp[3] = v.w;
    }
    __syncthreads();

    const int eg = tid >> 4, cg = tid & 15;
    const int e0 = eg * 8, c0 = cg * 8;

    float acc[8][8];
#pragma unroll
    for (int i = 0; i < 8; ++i)
#pragma unroll
        for (int j = 0; j < 8; ++j) acc[i][j] = 0.0f;

#pragma unroll 4
    for (int k = 0; k < H; ++k) {
        float a[8];
#pragma unroll
        for (int i = 0; i < 8; ++i) a[i] = at[(e0 + i) * 133 + k];
        const float4 b0 = *(const float4*)(W + (size_t)k * H + c0);
        const float4 b1 = *(const float4*)(W + (size_t)k * H + c0 + 4);
        const float bb[8] = {b0.x, b0.y, b0.z, b0.w, b1.x, b1.y, b1.z, b1.w};
#pragma unroll
        for (int i = 0; i < 8; ++i)
#pragma unroll
            for (int j = 0; j < 8; ++j) acc[i][j] = fmaf(a[i], bb[j], acc[i][j]);
    }

#pragma unroll
    for (int ei = 0; ei < 8; ++ei) {
        const int row = abase + e0 + ei;
        float* op = out + (size_t)row * H + c0;
        *(float4*)(op)     = make_float4(acc[ei][0], acc[ei][1], acc[ei][2], acc[ei][3]);
        *(float4*)(op + 4) = make_float4(acc[ei][4], acc[ei][5], acc[ei][6], acc[ei][7]);
    }
}

// ---------------- fused tail: x += tanh(agg@lin2+b2)@linw + bl ; h = x_new@lin1_next ----------------
template <bool MAKE_H>
__global__ __launch_bounds__(128, 2) void k_tail(const float* __restrict__ agg,
                                                 const float* __restrict__ lin2,
                                                 const float* __restrict__ b2,
                                                 const float* __restrict__ linw,
                                                 const float* __restrict__ bl,
                                                 float* __restrict__ x,
                                                 const float* __restrict__ lin1n,
                                                 float* __restrict__ hout) {
    __shared__ float at[64 * 133];
    const int tid = threadIdx.x;
    const int abase = blockIdx.x * 64;

#pragma unroll
    for (int i = 0; i < 16; ++i) {
        int flat4 = tid + 128 * i;
        int r = flat4 >> 5, k4 = flat4 & 31;
        float4 v = ((const float4*)(agg + (size_t)(abase + r) * H))[k4];
        float* dp = &at[r * 133 + k4 * 4];
        dp[0] = v.x; dp[1] = v.y; dp[2] = v.z; dp[3] = v.w;
    }
    __syncthreads();

    const int eg = tid >> 4, cg = tid & 15;
    const int e0 = eg * 8, c0 = cg * 8;

    float acc[8][8];
#pragma unroll
    for (int i = 0; i < 8; ++i)
#pragma unroll
        for (int j = 0; j < 8; ++j) acc[i][j] = 0.0f;

    // stage 1: agg @ lin2, tanh
#pragma unroll 4
    for (int k = 0; k < H; ++k) {
        float a[8];
#pragma unroll
        for (int i = 0; i < 8; ++i) a[i] = at[(e0 + i) * 133 + k];
        const float4 b0 = *(const float4*)(lin2 + (size_t)k * H + c0);
        const float4 b1 = *(const float4*)(lin2 + (size_t)k * H + c0 + 4);
        const float bb[8] = {b0.x, b0.y, b0.z, b0.w, b1.x, b1.y, b1.z, b1.w};
#pragma unroll
        for (int i = 0; i < 8; ++i)
#pragma unroll
            for (int j = 0; j < 8; ++j) acc[i][j] = fmaf(a[i], bb[j], acc[i][j]);
    }
    {
        const float4 q0 = *(const float4*)(b2 + c0);
        const float4 q1 = *(const float4*)(b2 + c0 + 4);
        const float bv[8] = {q0.x, q0.y, q0.z, q0.w, q1.x, q1.y, q1.z, q1.w};
#pragma unroll
        for (int i = 0; i < 8; ++i)
#pragma unroll
            for (int j = 0; j < 8; ++j) acc[i][j] = fast_tanh(acc[i][j] + bv[j]);
    }

    __syncthreads();
#pragma unroll
    for (int i = 0; i < 8; ++i)
#pragma unroll
        for (int j = 0; j < 8; ++j) at[(e0 + i) * 133 + c0 + j] = acc[i][j];
    __syncthreads();

    // stage 2: t @ linw, x += . + bl
#pragma unroll
    for (int i = 0; i < 8; ++i)
#pragma unroll
        for (int j = 0; j < 8; ++j) acc[i][j] = 0.0f;

#pragma unroll 4
    for (int k = 0; k < H; ++k) {
        float a[8];
#pragma unroll
        for (int i = 0; i < 8; ++i) a[i] = at[(e0 + i) * 133 + k];
        const float4 b0 = *(const float4*)(linw + (size_t)k * H + c0);
        const float4 b1 = *(const float4*)(linw + (size_t)k * H + c0 + 4);
        const float bb[8] = {b0.x, b0.y, b0.z, b0.w, b1.x, b1.y, b1.z, b1.w};
#pragma unroll
        for (int i = 0; i < 8; ++i)
#pragma unroll
            for (int j = 0; j < 8; ++j) acc[i][j] = fmaf(a[i], bb[j], acc[i][j]);
    }

    {
        const float4 q0 = *(const float4*)(bl + c0);
        const float4 q1 = *(const float4*)(bl + c0 + 4);
        const float bv[8] = {q0.x, q0.y, q0.z, q0.w, q1.x, q1.y, q1.z, q1.w};
        if (MAKE_H) __syncthreads();  // all stage-2 reads of at done before overwrite
#pragma unroll
        for (int ei = 0; ei < 8; ++ei) {
            const int row = abase + e0 + ei;
            float* op = x + (size_t)row * H + c0;
            float4 x0 = *(const float4*)(op);
            float4 x1 = *(const float4*)(op + 4);
            float xn[8] = {x0.x + acc[ei][0] + bv[0], x0.y + acc[ei][1] + bv[1],
                           x0.z + acc[ei][2] + bv[2], x0.w + acc[ei][3] + bv[3],
                           x1.x + acc[ei][4] + bv[4], x1.y + acc[ei][5] + bv[5],
                           x1.z + acc[ei][6] + bv[6], x1.w + acc[ei][7] + bv[7]};
            *(float4*)(op)     = make_float4(xn[0], xn[1], xn[2], xn[3]);
            *(float4*)(op + 4) = make_float4(xn[4], xn[5], xn[6], xn[7]);
            if (MAKE_H) {
#pragma unroll
                for (int j = 0; j < 8; ++j) at[(e0 + ei) * 133 + c0 + j] = xn[j];
            }
        }
    }

    if (MAKE_H) {
        __syncthreads();
        // stage 3: h = x_new @ lin1_next
#pragma unroll
        for (int i = 0; i < 8; ++i)
#pragma unroll
            for (int j = 0; j < 8; ++j) acc[i][j] = 0.0f;

#pragma unroll 4
        for (int k = 0; k < H; ++k) {
            float a[8];
#pragma unroll
            for (int i = 0; i < 8; ++i) a[i] = at[(e0 + i) * 133 + k];
            const float4 b0 = *(const float4*)(lin1n + (size_t)k * H + c0);
            const float4 b1 = *(const float4*)(lin1n + (size_t)k * H + c0 + 4);
            const float bb[8] = {b0.x, b0.y, b0.z, b0.w, b1.x, b1.y, b1.z, b1.w};
#pragma unroll
            for (int i = 0; i < 8; ++i)
#pragma unroll
                for (int j = 0; j < 8; ++j) acc[i][j] = fmaf(a[i], bb[j], acc[i][j]);
        }

#pragma unroll
        for (int ei = 0; ei < 8; ++ei) {
            const int row = abase + e0 + ei;
            float* op = hout + (size_t)row * H + c0;
            *(float4*)(op)     = make_float4(acc[ei][0], acc[ei][1], acc[ei][2], acc[ei][3]);
            *(float4*)(op + 4) = make_float4(acc[ei][4], acc[ei][5], acc[ei][6], acc[ei][7]);
        }
    }
}

// ---------------- K2: atom-centric gather-aggregate, shfl-broadcast meta ----------------
__global__ __launch_bounds__(256) void k_edge4(const int* __restrict__ rstart,
                                               const int* __restrict__ rend,
                                               const int2* __restrict__ pmeta,
                                               const float* __restrict__ tab,
                                               const float* __restrict__ h,
                                               float* __restrict__ agg) {
    const int wave = threadIdx.x >> 6;
    const int lane = threadIdx.x & 63;
    const int a = blockIdx.x * 4 + wave;
    const int col0 = lane * 2;

    const int s = rstart[a];
    const int n = rend[a] - s;

    float s0 = 0.0f, s1 = 0.0f;
    if (n <= 64) {
        // one coalesced meta load for the whole row, broadcast by shfl
        int2 meta = make_int2(0, 0);
        if (lane < n) meta = pmeta[s + lane];
#pragma unroll 2
        for (int e = 0; e < n; ++e) {
            const int src = __shfl(meta.x, e, 64);
            const float u = __int_as_float(__shfl(meta.y, e, 64));
            int i0 = (int)u;
            i0 = (i0 > TBL - 2) ? (TBL - 2) : i0;
            const float f = u - (float)i0;
            const float2 lo = *(const float2*)(tab + (size_t)i0 * H + col0);
            const float2 hi = *(const float2*)(tab + ((size_t)i0 + 1) * H + col0);
            const float2 hv = *(const float2*)(h + (size_t)src * H + col0);
            s0 = fmaf(fmaf(f, hi.x - lo.x, lo.x), hv.x, s0);
            s1 = fmaf(fmaf(f, hi.y - lo.y, lo.y), hv.y, s1);
        }
    } else {
        for (int e = s; e < s + n; ++e) {
            const int2 m = pmeta[e];
            const float u = __int_as_float(m.y);
            int i0 = (int)u;
            i0 = (i0 > TBL - 2) ? (TBL - 2) : i0;
            const float f = u - (float)i0;
            const float2 lo = *(const float2*)(tab + (size_t)i0 * H + col0);
            const float2 hi = *(const float2*)(tab + ((size_t)i0 + 1) * H + col0);
            const float2 hv = *(const float2*)(h + (size_t)m.x * H + col0);
            s0 = fmaf(fmaf(f, hi.x - lo.x, lo.x), hv.x, s0);
            s1 = fmaf(fmaf(f, hi.y - lo.y, lo.y), hv.y, s1);
        }
    }
    *(float2*)(agg + (size_t)a * H + col0) = make_float2(s0, s1);
}

// ---------------- K5: energy, 64 atoms x 64 cols per 256-thread block ----------------
__global__ __launch_bounds__(256) void k_out(const float* __restrict__ x,
                                             const float* __restrict__ o1w,
                                             const float* __restrict__ o1b,
                                             const float* __restrict__ o2w,
                                             const float* __restrict__ o2b,
                                             float* __restrict__ out) {
    __shared__ float xs[64 * 132];
    const int tid = threadIdx.x;
    const int abase = blockIdx.x * 64;

#pragma unroll
    for (int i = 0; i < 8; ++i) {
        int flat4 = tid + 256 * i;
        int r = flat4 >> 5, k4 = flat4 & 31;
        float4 v = ((const float4*)(x + (size_t)(abase + r) * H))[k4];
        float* dp = &xs[r * 132 + k4 * 4];
        dp[0] = v.x; dp[1] = v.y; dp[2] = v.z; dp[3] = v.w;
    }
    __syncthreads();

    const int eg = tid >> 4, cg = tid & 15;
    const int r0 = eg * 4, c0 = cg * 4;

    float acc[4][4];
#pragma unroll
    for (int i = 0; i < 4; ++i)
#pragma unroll
        for (int j = 0; j < 4; ++j) acc[i][j] = 0.0f;

#pragma unroll 4
    for (int k = 0; k < H; ++k) {
        float a[4];
#pragma unroll
        for (int i = 0; i < 4; ++i) a[i] = xs[(r0 + i) * 132 + k];
        const float4 b = *(const float4*)(o1w + (size_t)k * 64 + c0);
        const float bb[4] = {b.x, b.y, b.z, b.w};
#pragma unroll
        for (int i = 0; i < 4; ++i)
#pragma unroll
            for (int j = 0; j < 4; ++j) acc[i][j] = fmaf(a[i], bb[j], acc[i][j]);
    }

    const float4 ob = *(const float4*)(o1b + c0);
    const float4 ow = *(const float4*)(o2w + c0);
    const float obv[4] = {ob.x, ob.y, ob.z, ob.w};
    const float owv[4] = {ow.x, ow.y, ow.z, ow.w};
    float p[4];
#pragma unroll
    for (int i = 0; i < 4; ++i) {
        float s = 0.0f;
#pragma unroll
        for (int j = 0; j < 4; ++j) s = fmaf(fast_tanh(acc[i][j] + obv[j]), owv[j], s);
        p[i] = s;
    }
#pragma unroll
    for (int off = 1; off < 16; off <<= 1) {
#pragma unroll
        for (int i = 0; i < 4; ++i) p[i] += __shfl_xor(p[i], off, 64);
    }
    if (cg == 0) {
        const float b2 = o2b[0];
#pragma unroll
        for (int i = 0; i < 4; ++i) out[abase + r0 + i] = p[i] + b2;
    }
}

extern "C" void kernel_launch(void* const* d_in, const int* in_sizes, int n_in,
                              void* d_out, int out_size, void* d_ws, size_t ws_size,
                              hipStream_t stream) {
    const int*   types = (const int*)d_in[0];
    const int*   eidx  = (const int*)d_in[1];
    const float* ew    = (const float*)d_in[2];
    const float* emb   = (const float*)d_in[3];
    const float* lin1  = (const float*)d_in[4];
    const float* fw1   = (const float*)d_in[5];
    const float* fb1   = (const float*)d_in[6];
    const float* fw2   = (const float*)d_in[7];
    const float* fb2   = (const float*)d_in[8];
    const float* lin2  = (const float*)d_in[9];
    const float* lin2b = (const float*)d_in[10];
    const float* linw  = (const float*)d_in[11];
    const float* linb  = (const float*)d_in[12];
    const float* o1w   = (const float*)d_in[13];
    const float* o1b   = (const float*)d_in[14];
    const float* o2w   = (const float*)d_in[15];
    const float* o2b   = (const float*)d_in[16];
    float* out = (float*)d_out;

    // ws carve
    float* x      = (float*)d_ws;                            // N*H
    float* h      = x + (size_t)N_ATOMS * H;                 // N*H
    float* agg    = h + (size_t)N_ATOMS * H;                 // N*H
    float* tab    = agg + (size_t)N_ATOMS * H;               // NBLK*TBL*H
    int*   cnt    = (int*)(tab + (size_t)NBLK * TBL * H);    // N
    int*   cursor = cnt + N_ATOMS;                           // N
    int*   rstart = cursor + N_ATOMS;                        // N
    int*   bsum   = rstart + N_ATOMS;                        // 40 (pad 64)
    int*   boff   = bsum + 64;                               // 40 (pad 64)
    int2*  pmeta  = (int2*)(boff + 64);                      // E

    // ---- CSR build ----
    hipMemsetAsync(cnt, 0, N_ATOMS * sizeof(int), stream);
    k_count<<<E_EDGES / 256, 256, 0, stream>>>(eidx, cnt);
    k_scanA<<<40, 1024, 0, stream>>>(cnt, bsum);
    k_scanB<<<1, 64, 0, stream>>>(bsum, boff);
    k_scanC<<<40, 1024, 0, stream>>>(cnt, boff, cursor, rstart);
    k_fill<<<E_EDGES / 256, 256, 0, stream>>>(eidx, ew, cursor, pmeta);
    // after k_fill, cursor[a] == row end of atom a

    // ---- embed + filter tables ----
    k_embed<<<(N_ATOMS * H / 4) / 256, 256, 0, stream>>>(types, emb, x);
    k_table<<<dim3(TBL / 128, NBLK), 256, 0, stream>>>(fw1, fb1, fw2, fb2, tab);

    // h for block 0
    k_gemm_nh<<<N_ATOMS / 64, 128, 0, stream>>>(x, lin1, h);

    for (int b = 0; b < NBLK; ++b) {
        k_edge4<<<N_ATOMS / 4, 256, 0, stream>>>(rstart, cursor, pmeta,
                                                 tab + (size_t)b * TBL * H, h, agg);
        if (b < NBLK - 1) {
            k_tail<true><<<N_ATOMS / 64, 128, 0, stream>>>(
                agg, lin2 + (size_t)b * H * H, lin2b + (size_t)b * H,
                linw + (size_t)b * H * H, linb + (size_t)b * H, x,
                lin1 + (size_t)(b + 1) * H * H, h);
        } else {
            k_tail<false><<<N_ATOMS / 64, 128, 0, stream>>>(
                agg, lin2 + (size_t)b * H * H, lin2b + (size_t)b * H,
                linw + (size_t)b * H * H, linb + (size_t)b * H, x,
                nullptr, nullptr);
        }
    }

    k_out<<<N_ATOMS / 64, 256, 0, stream>>>(x, o1w, o1b, o2w, o2b, out);
}

// Round 6
// 639.356 us; speedup vs baseline: 11.6415x; 1.0402x over previous
//
#include <hip/hip_runtime.h>
#include <math.h>

#define N_ATOMS 40000
#define E_EDGES 640000
#define H 128
#define RBF 64
#define NBLK 3
#define CUTF 5.0f
#define TBL 4096   // filter lookup table entries per block (2 MB -> L2-resident)

// stable fast tanh: exp-based, saturates correctly at +/-inf
__device__ __forceinline__ float fast_tanh(float x) {
    return 1.0f - 2.0f / (1.0f + __expf(2.0f * x));
}

// ---------------- embW = emb @ lin1[0]  (100 x 128) ----------------
__global__ __launch_bounds__(128) void k_embw(const float* __restrict__ emb,
                                              const float* __restrict__ lin1,
                                              float* __restrict__ embw) {
    const int t = blockIdx.x;
    const int c = threadIdx.x;
    float s = 0.0f;
#pragma unroll 8
    for (int k = 0; k < H; ++k) s = fmaf(emb[t * H + k], lin1[(size_t)k * H + c], s);
    embw[t * H + c] = s;
}

// ---------------- K0: x = emb[atom_types]; h = embW[atom_types] ----------------
__global__ __launch_bounds__(256) void k_embed2(const int* __restrict__ types,
                                                const float* __restrict__ emb,
                                                const float* __restrict__ embw,
                                                float* __restrict__ x,
                                                float* __restrict__ h) {
    int flat4 = blockIdx.x * 256 + threadIdx.x;  // over N*H/4
    int i = flat4 >> 5;
    int c4 = flat4 & 31;
    int t = types[i];
    ((float4*)(x + (size_t)i * H))[c4] = ((const float4*)(emb + (size_t)t * H))[c4];
    ((float4*)(h + (size_t)i * H))[c4] = ((const float4*)(embw + (size_t)t * H))[c4];
}

// ---------------- CSR build ----------------
__global__ __launch_bounds__(256) void k_count(const int* __restrict__ eidx,
                                               int* __restrict__ cnt) {
    int e = blockIdx.x * 256 + threadIdx.x;
    atomicAdd(&cnt[eidx[E_EDGES + e]], 1);
}

__global__ __launch_bounds__(1024) void k_scanA(const int* __restrict__ cnt,
                                                int* __restrict__ bsum) {
    __shared__ int ws[16];
    const int tid = threadIdx.x, lane = tid & 63, wid = tid >> 6;
    int idx = blockIdx.x * 1024 + tid;
    int v = (idx < N_ATOMS) ? cnt[idx] : 0;
#pragma unroll
    for (int off = 32; off; off >>= 1) v += __shfl_xor(v, off, 64);
    if (lane == 0) ws[wid] = v;
    __syncthreads();
    if (tid == 0) {
        int s = 0;
#pragma unroll
        for (int w = 0; w < 16; ++w) s += ws[w];
        bsum[blockIdx.x] = s;
    }
}

__global__ __launch_bounds__(64) void k_scanB(const int* __restrict__ bsum,
                                              int* __restrict__ boff) {
    const int lane = threadIdx.x;
    int v = (lane < 40) ? bsum[lane] : 0;
    int inc = v;
#pragma unroll
    for (int off = 1; off < 64; off <<= 1) {
        int t = __shfl_up(inc, off, 64);
        if (lane >= off) inc += t;
    }
    if (lane < 40) boff[lane] = inc - v;
}

__global__ __launch_bounds__(1024) void k_scanC(const int* __restrict__ cnt,
                                                const int* __restrict__ boff,
                                                int* __restrict__ cursor,
                                                int* __restrict__ rstart) {
    __shared__ int wsum[16];
    __shared__ int woff[16];
    const int tid = threadIdx.x, lane = tid & 63, wid = tid >> 6;
    int idx = blockIdx.x * 1024 + tid;
    int v = (idx < N_ATOMS) ? cnt[idx] : 0;
    int inc = v;
#pragma unroll
    for (int off = 1; off < 64; off <<= 1) {
        int t = __shfl_up(inc, off, 64);
        if (lane >= off) inc += t;
    }
    if (lane == 63) wsum[wid] = inc;
    __syncthreads();
    if (tid == 0) {
        int acc = 0;
#pragma unroll
        for (int w = 0; w < 16; ++w) { woff[w] = acc; acc += wsum[w]; }
    }
    __syncthreads();
    if (idx < N_ATOMS) {
        int ex = boff[blockIdx.x] + woff[wid] + inc - v;
        cursor[idx] = ex;
        rstart[idx] = ex;
    }
}

// fill: pmeta[pos] = {src, float_bits(u)}, u = d*(TBL-1)/CUT (dst-sorted)
__global__ __launch_bounds__(256) void k_fill(const int* __restrict__ eidx,
                                              const float* __restrict__ ew,
                                              int* __restrict__ cursor,
                                              int2* __restrict__ pmeta) {
    int e = blockIdx.x * 256 + threadIdx.x;
    int dd = eidx[E_EDGES + e];
    int pos = atomicAdd(&cursor[dd], 1);
    float u = ew[e] * ((float)(TBL - 1) / CUTF);
    pmeta[pos] = make_int2(eidx[e], __float_as_int(u));
}

// ---------------- K1: filter table build ----------------
__global__ __launch_bounds__(256, 2) void k_table(const float* __restrict__ fw1all,
                                                  const float* __restrict__ fb1all,
                                                  const float* __restrict__ fw2all,
                                                  const float* __restrict__ fb2all,
                                                  float* __restrict__ tab) {
    const int b = blockIdx.y;
    const float* fw1 = fw1all + (size_t)b * RBF * H;
    const float* fb1 = fb1all + (size_t)b * H;
    const float* fw2 = fw2all + (size_t)b * H * H;
    const float* fb2 = fb2all + (size_t)b * H;
    float* tabB = tab + (size_t)b * TBL * H;

    __shared__ float tile[128 * 133];
    const int tid = threadIdx.x;
    const int mbase = blockIdx.x * 128;
    const float DSTEP = CUTF / (float)(TBL - 1);

    {
        const int e = tid & 127;
        const int k0 = (tid >> 7) * 32;
        const float d = (float)(mbase + e) * DSTEP;
        const float DELTA = CUTF / 63.0f;
        const float COEFF = -0.5f / (DELTA * DELTA);
#pragma unroll
        for (int k = k0; k < k0 + 32; ++k) {
            float diff = d - (float)k * DELTA;
            tile[e * 133 + k] = __expf(COEFF * diff * diff);
        }
    }
    __syncthreads();

    const int eg = tid >> 4, cg = tid & 15;
    const int e0 = eg * 8, c0 = cg * 8;

    float acc[8][8];
#pragma unroll
    for (int i = 0; i < 8; ++i)
#pragma unroll
        for (int j = 0; j < 8; ++j) acc[i][j] = 0.0f;

#pragma unroll 4
    for (int k = 0; k < RBF; ++k) {
        float a[8];
#pragma unroll
        for (int i = 0; i < 8; ++i) a[i] = tile[(e0 + i) * 133 + k];
        const float4 b0 = *(const float4*)(fw1 + (size_t)k * H + c0);
        const float4 b1 = *(const float4*)(fw1 + (size_t)k * H + c0 + 4);
        const float bb[8] = {b0.x, b0.y, b0.z, b0.w, b1.x, b1.y, b1.z, b1.w};
#pragma unroll
        for (int i = 0; i < 8; ++i)
#pragma unroll
            for (int j = 0; j < 8; ++j) acc[i][j] = fmaf(a[i], bb[j], acc[i][j]);
    }

    {
        const float4 q0 = *(const float4*)(fb1 + c0);
        const float4 q1 = *(const float4*)(fb1 + c0 + 4);
        const float bv[8] = {q0.x, q0.y, q0.z, q0.w, q1.x, q1.y, q1.z, q1.w};
#pragma unroll
        for (int i = 0; i < 8; ++i)
#pragma unroll
            for (int j = 0; j < 8; ++j) acc[i][j] = fast_tanh(acc[i][j] + bv[j]);
    }

    __syncthreads();
#pragma unroll
    for (int i = 0; i < 8; ++i)
#pragma unroll
        for (int j = 0; j < 8; ++j) tile[(e0 + i) * 133 + c0 + j] = acc[i][j];
    __syncthreads();

#pragma unroll
    for (int i = 0; i < 8; ++i)
#pragma unroll
        for (int j = 0; j < 8; ++j) acc[i][j] = 0.0f;

#pragma unroll 4
    for (int k = 0; k < H; ++k) {
        float a[8];
#pragma unroll
        for (int i = 0; i < 8; ++i) a[i] = tile[(e0 + i) * 133 + k];
        const float4 b0 = *(const float4*)(fw2 + (size_t)k * H + c0);
        const float4 b1 = *(const float4*)(fw2 + (size_t)k * H + c0 + 4);
        const float bb[8] = {b0.x, b0.y, b0.z, b0.w, b1.x, b1.y, b1.z, b1.w};
#pragma unroll
        for (int i = 0; i < 8; ++i)
#pragma unroll
            for (int j = 0; j < 8; ++j) acc[i][j] = fmaf(a[i], bb[j], acc[i][j]);
    }

    const float4 q0 = *(const float4*)(fb2 + c0);
    const float4 q1 = *(const float4*)(fb2 + c0 + 4);
    const float bv[8] = {q0.x, q0.y, q0.z, q0.w, q1.x, q1.y, q1.z, q1.w};

#pragma unroll
    for (int ei = 0; ei < 8; ++ei) {
        const int m = mbase + e0 + ei;
        const float d = (float)m * DSTEP;
        float c = 0.5f * (cosf(0.6283185307179586f * d) + 1.0f);
        c = (d < CUTF) ? c : 0.0f;
        float* op = tabB + (size_t)m * H + c0;
        float r[8];
#pragma unroll
        for (int j = 0; j < 8; ++j) r[j] = (acc[ei][j] + bv[j]) * c;
        *(float4*)(op)     = make_float4(r[0], r[1], r[2], r[3]);
        *(float4*)(op + 4) = make_float4(r[4], r[5], r[6], r[7]);
    }
}

// ---------------- fused tail (256 thr, 64-atom tile, 4x8 micro):
// x += tanh(agg@lin2+b2)@linw + bl ; optionally h = x_new@lin1_next
template <bool MAKE_H>
__global__ __launch_bounds__(256) void k_tail(const float* __restrict__ agg,
                                              const float* __restrict__ lin2,
                                              const float* __restrict__ b2,
                                              const float* __restrict__ linw,
                                              const float* __restrict__ bl,
                                              float* __restrict__ x,
                                              const float* __restrict__ lin1n,
                                              float* __restrict__ hout) {
    __shared__ float at[64 * 133];
    const int tid = threadIdx.x;
    const int abase = blockIdx.x * 64;

    // stage agg tile [64][128] -> LDS
#pragma unroll
    for (int i = 0; i < 8; ++i) {
        int flat4 = tid + 256 * i;
        int r = flat4 >> 5, k4 = flat4 & 31;
        float4 v = ((const float4*)(agg + (size_t)(abase + r) * H))[k4];
        float* dp = &at[r * 133 + k4 * 4];
        dp[0] = v.x; dp[1] = v.y; dp[2] = v.z; dp[3] = v.w;
    }
    __syncthreads();

    const int eg = tid >> 4, cg = tid & 15;   // 16 x 16 thread grid
    const int r0 = eg * 4, c0 = cg * 8;       // 4 rows x 8 cols per thread

    float acc[4][8];
#pragma unroll
    for (int i = 0; i < 4; ++i)
#pragma unroll
        for (int j = 0; j < 8; ++j) acc[i][j] = 0.0f;

    // stage 1: agg @ lin2, tanh
#pragma unroll 4
    for (int k = 0; k < H; ++k) {
        float a[4];
#pragma unroll
        for (int i = 0; i < 4; ++i) a[i] = at[(r0 + i) * 133 + k];
        const float4 b0 = *(const float4*)(lin2 + (size_t)k * H + c0);
        const float4 b1 = *(const float4*)(lin2 + (size_t)k * H + c0 + 4);
        const float bb[8] = {b0.x, b0.y, b0.z, b0.w, b1.x, b1.y, b1.z, b1.w};
#pragma unroll
        for (int i = 0; i < 4; ++i)
#pragma unroll
            for (int j = 0; j < 8; ++j) acc[i][j] = fmaf(a[i], bb[j], acc[i][j]);
    }
    {
        const float4 q0 = *(const float4*)(b2 + c0);
        const float4 q1 = *(const float4*)(b2 + c0 + 4);
        const float bv[8] = {q0.x, q0.y, q0.z, q0.w, q1.x, q1.y, q1.z, q1.w};
#pragma unroll
        for (int i = 0; i < 4; ++i)
#pragma unroll
            for (int j = 0; j < 8; ++j) acc[i][j] = fast_tanh(acc[i][j] + bv[j]);
    }

    __syncthreads();
#pragma unroll
    for (int i = 0; i < 4; ++i)
#pragma unroll
        for (int j = 0; j < 8; ++j) at[(r0 + i) * 133 + c0 + j] = acc[i][j];
    __syncthreads();

    // stage 2: t @ linw
#pragma unroll
    for (int i = 0; i < 4; ++i)
#pragma unroll
        for (int j = 0; j < 8; ++j) acc[i][j] = 0.0f;

#pragma unroll 4
    for (int k = 0; k < H; ++k) {
        float a[4];
#pragma unroll
        for (int i = 0; i < 4; ++i) a[i] = at[(r0 + i) * 133 + k];
        const float4 b0 = *(const float4*)(linw + (size_t)k * H + c0);
        const float4 b1 = *(const float4*)(linw + (size_t)k * H + c0 + 4);
        const float bb[8] = {b0.x, b0.y, b0.z, b0.w, b1.x, b1.y, b1.z, b1.w};
#pragma unroll
        for (int i = 0; i < 4; ++i)
#pragma unroll
            for (int j = 0; j < 8; ++j) acc[i][j] = fmaf(a[i], bb[j], acc[i][j]);
    }

    {
        const float4 q0 = *(const float4*)(bl + c0);
        const float4 q1 = *(const float4*)(bl + c0 + 4);
        const float bv[8] = {q0.x, q0.y, q0.z, q0.w, q1.x, q1.y, q1.z, q1.w};
        if (MAKE_H) __syncthreads();  // all stage-2 reads of at done before overwrite
#pragma unroll
        for (int ei = 0; ei < 4; ++ei) {
            const int row = abase + r0 + ei;
            float* op = x + (size_t)row * H + c0;
            float4 x0 = *(const float4*)(op);
            float4 x1 = *(const float4*)(op + 4);
            float xn[8] = {x0.x + acc[ei][0] + bv[0], x0.y + acc[ei][1] + bv[1],
                           x0.z + acc[ei][2] + bv[2], x0.w + acc[ei][3] + bv[3],
                           x1.x + acc[ei][4] + bv[4], x1.y + acc[ei][5] + bv[5],
                           x1.z + acc[ei][6] + bv[6], x1.w + acc[ei][7] + bv[7]};
            *(float4*)(op)     = make_float4(xn[0], xn[1], xn[2], xn[3]);
            *(float4*)(op + 4) = make_float4(xn[4], xn[5], xn[6], xn[7]);
            if (MAKE_H) {
#pragma unroll
                for (int j = 0; j < 8; ++j) at[(r0 + ei) * 133 + c0 + j] = xn[j];
            }
        }
    }

    if (MAKE_H) {
        __syncthreads();
        // stage 3: h = x_new @ lin1_next
        float acc3[4][8];
#pragma unroll
        for (int i = 0; i < 4; ++i)
#pragma unroll
            for (int j = 0; j < 8; ++j) acc3[i][j] = 0.0f;

#pragma unroll 4
        for (int k = 0; k < H; ++k) {
            float a[4];
#pragma unroll
            for (int i = 0; i < 4; ++i) a[i] = at[(r0 + i) * 133 + k];
            const float4 b0 = *(const float4*)(lin1n + (size_t)k * H + c0);
            const float4 b1 = *(const float4*)(lin1n + (size_t)k * H + c0 + 4);
            const float bb[8] = {b0.x, b0.y, b0.z, b0.w, b1.x, b1.y, b1.z, b1.w};
#pragma unroll
            for (int i = 0; i < 4; ++i)
#pragma unroll
                for (int j = 0; j < 8; ++j) acc3[i][j] = fmaf(a[i], bb[j], acc3[i][j]);
        }

#pragma unroll
        for (int ei = 0; ei < 4; ++ei) {
            const int row = abase + r0 + ei;
            float* op = hout + (size_t)row * H + c0;
            *(float4*)(op)     = make_float4(acc3[ei][0], acc3[ei][1], acc3[ei][2], acc3[ei][3]);
            *(float4*)(op + 4) = make_float4(acc3[ei][4], acc3[ei][5], acc3[ei][6], acc3[ei][7]);
        }
    }
}

// ---------------- K2: atom-centric gather-aggregate, shfl-broadcast meta ----------------
__global__ __launch_bounds__(256) void k_edge4(const int* __restrict__ rstart,
                                               const int* __restrict__ rend,
                                               const int2* __restrict__ pmeta,
                                               const float* __restrict__ tab,
                                               const float* __restrict__ h,
                                               float* __restrict__ agg) {
    const int wave = threadIdx.x >> 6;
    const int lane = threadIdx.x & 63;
    const int a = blockIdx.x * 4 + wave;
    const int col0 = lane * 2;

    const int s = rstart[a];
    const int n = rend[a] - s;

    float s0 = 0.0f, s1 = 0.0f;
    if (n <= 64) {
        int2 meta = make_int2(0, 0);
        if (lane < n) meta = pmeta[s + lane];
#pragma unroll 2
        for (int e = 0; e < n; ++e) {
            const int src = __shfl(meta.x, e, 64);
            const float u = __int_as_float(__shfl(meta.y, e, 64));
            int i0 = (int)u;
            i0 = (i0 > TBL - 2) ? (TBL - 2) : i0;
            const float f = u - (float)i0;
            const float2 lo = *(const float2*)(tab + (size_t)i0 * H + col0);
            const float2 hi = *(const float2*)(tab + ((size_t)i0 + 1) * H + col0);
            const float2 hv = *(const float2*)(h + (size_t)src * H + col0);
            s0 = fmaf(fmaf(f, hi.x - lo.x, lo.x), hv.x, s0);
            s1 = fmaf(fmaf(f, hi.y - lo.y, lo.y), hv.y, s1);
        }
    } else {
        for (int e = s; e < s + n; ++e) {
            const int2 m = pmeta[e];
            const float u = __int_as_float(m.y);
            int i0 = (int)u;
            i0 = (i0 > TBL - 2) ? (TBL - 2) : i0;
            const float f = u - (float)i0;
            const float2 lo = *(const float2*)(tab + (size_t)i0 * H + col0);
            const float2 hi = *(const float2*)(tab + ((size_t)i0 + 1) * H + col0);
            const float2 hv = *(const float2*)(h + (size_t)m.x * H + col0);
            s0 = fmaf(fmaf(f, hi.x - lo.x, lo.x), hv.x, s0);
            s1 = fmaf(fmaf(f, hi.y - lo.y, lo.y), hv.y, s1);
        }
    }
    *(float2*)(agg + (size_t)a * H + col0) = make_float2(s0, s1);
}

// ---------------- K5: energy, 64 atoms x 64 cols per 256-thread block ----------------
__global__ __launch_bounds__(256) void k_out(const float* __restrict__ x,
                                             const float* __restrict__ o1w,
                                             const float* __restrict__ o1b,
                                             const float* __restrict__ o2w,
                                             const float* __restrict__ o2b,
                                             float* __restrict__ out) {
    __shared__ float xs[64 * 132];
    const int tid = threadIdx.x;
    const int abase = blockIdx.x * 64;

#pragma unroll
    for (int i = 0; i < 8; ++i) {
        int flat4 = tid + 256 * i;
        int r = flat4 >> 5, k4 = flat4 & 31;
        float4 v = ((const float4*)(x + (size_t)(abase + r) * H))[k4];
        float* dp = &xs[r * 132 + k4 * 4];
        dp[0] = v.x; dp[1] = v.y; dp[2] = v.z; dp[3] = v.w;
    }
    __syncthreads();

    const int eg = tid >> 4, cg = tid & 15;
    const int r0 = eg * 4, c0 = cg * 4;

    float acc[4][4];
#pragma unroll
    for (int i = 0; i < 4; ++i)
#pragma unroll
        for (int j = 0; j < 4; ++j) acc[i][j] = 0.0f;

#pragma unroll 4
    for (int k = 0; k < H; ++k) {
        float a[4];
#pragma unroll
        for (int i = 0; i < 4; ++i) a[i] = xs[(r0 + i) * 132 + k];
        const float4 b = *(const float4*)(o1w + (size_t)k * 64 + c0);
        const float bb[4] = {b.x, b.y, b.z, b.w};
#pragma unroll
        for (int i = 0; i < 4; ++i)
#pragma unroll
            for (int j = 0; j < 4; ++j) acc[i][j] = fmaf(a[i], bb[j], acc[i][j]);
    }

    const float4 ob = *(const float4*)(o1b + c0);
    const float4 ow = *(const float4*)(o2w + c0);
    const float obv[4] = {ob.x, ob.y, ob.z, ob.w};
    const float owv[4] = {ow.x, ow.y, ow.z, ow.w};
    float p[4];
#pragma unroll
    for (int i = 0; i < 4; ++i) {
        float s = 0.0f;
#pragma unroll
        for (int j = 0; j < 4; ++j) s = fmaf(fast_tanh(acc[i][j] + obv[j]), owv[j], s);
        p[i] = s;
    }
#pragma unroll
    for (int off = 1; off < 16; off <<= 1) {
#pragma unroll
        for (int i = 0; i < 4; ++i) p[i] += __shfl_xor(p[i], off, 64);
    }
    if (cg == 0) {
        const float b2 = o2b[0];
#pragma unroll
        for (int i = 0; i < 4; ++i) out[abase + r0 + i] = p[i] + b2;
    }
}

extern "C" void kernel_launch(void* const* d_in, const int* in_sizes, int n_in,
                              void* d_out, int out_size, void* d_ws, size_t ws_size,
                              hipStream_t stream) {
    const int*   types = (const int*)d_in[0];
    const int*   eidx  = (const int*)d_in[1];
    const float* ew    = (const float*)d_in[2];
    const float* emb   = (const float*)d_in[3];
    const float* lin1  = (const float*)d_in[4];
    const float* fw1   = (const float*)d_in[5];
    const float* fb1   = (const float*)d_in[6];
    const float* fw2   = (const float*)d_in[7];
    const float* fb2   = (const float*)d_in[8];
    const float* lin2  = (const float*)d_in[9];
    const float* lin2b = (const float*)d_in[10];
    const float* linw  = (const float*)d_in[11];
    const float* linb  = (const float*)d_in[12];
    const float* o1w   = (const float*)d_in[13];
    const float* o1b   = (const float*)d_in[14];
    const float* o2w   = (const float*)d_in[15];
    const float* o2b   = (const float*)d_in[16];
    float* out = (float*)d_out;

    // ws carve
    float* x      = (float*)d_ws;                            // N*H
    float* h      = x + (size_t)N_ATOMS * H;                 // N*H
    float* agg    = h + (size_t)N_ATOMS * H;                 // N*H
    float* tab    = agg + (size_t)N_ATOMS * H;               // NBLK*TBL*H
    float* embw   = tab + (size_t)NBLK * TBL * H;            // 100*H
    int*   cnt    = (int*)(embw + 100 * H);                  // N
    int*   cursor = cnt + N_ATOMS;                           // N
    int*   rstart = cursor + N_ATOMS;                        // N
    int*   bsum   = rstart + N_ATOMS;                        // 40 (pad 64)
    int*   boff   = bsum + 64;                               // 40 (pad 64)
    int2*  pmeta  = (int2*)(boff + 64);                      // E

    // ---- CSR build ----
    hipMemsetAsync(cnt, 0, N_ATOMS * sizeof(int), stream);
    k_count<<<E_EDGES / 256, 256, 0, stream>>>(eidx, cnt);
    k_scanA<<<40, 1024, 0, stream>>>(cnt, bsum);
    k_scanB<<<1, 64, 0, stream>>>(bsum, boff);
    k_scanC<<<40, 1024, 0, stream>>>(cnt, boff, cursor, rstart);
    k_fill<<<E_EDGES / 256, 256, 0, stream>>>(eidx, ew, cursor, pmeta);
    // after k_fill, cursor[a] == row end of atom a

    // ---- type-table h0, embed, filter tables ----
    k_embw<<<100, 128, 0, stream>>>(emb, lin1, embw);
    k_embed2<<<(N_ATOMS * H / 4) / 256, 256, 0, stream>>>(types, emb, embw, x, h);
    k_table<<<dim3(TBL / 128, NBLK), 256, 0, stream>>>(fw1, fb1, fw2, fb2, tab);

    for (int b = 0; b < NBLK; ++b) {
        k_edge4<<<N_ATOMS / 4, 256, 0, stream>>>(rstart, cursor, pmeta,
                                                 tab + (size_t)b * TBL * H, h, agg);
        if (b < NBLK - 1) {
            k_tail<true><<<N_ATOMS / 64, 256, 0, stream>>>(
                agg, lin2 + (size_t)b * H * H, lin2b + (size_t)b * H,
                linw + (size_t)b * H * H, linb + (size_t)b * H, x,
                lin1 + (size_t)(b + 1) * H * H, h);
        } else {
            k_tail<false><<<N_ATOMS / 64, 256, 0, stream>>>(
                agg, lin2 + (size_t)b * H * H, lin2b + (size_t)b * H,
                linw + (size_t)b * H * H, linb + (size_t)b * H, x,
                nullptr, nullptr);
        }
    }

    k_out<<<N_ATOMS / 64, 256, 0, stream>>>(x, o1w, o1b, o2w, o2b, out);
}